// Round 1
// baseline (961.017 us; speedup 1.0000x reference)
//
#include <hip/hip_runtime.h>
#include <hip/hip_bf16.h>

#define B_   32
#define C_   128
#define H_   56
#define W_   56
#define HW_  (H_*W_)
#define K5_  5
#define KK_  25
#define CR_  32
#define CE_  512
#define EPS_ 1e-6f

typedef __hip_bfloat16 bf16;

// ---------- workspace layout (bytes) ----------
// pooled  fp32 [B*C]              @ 0          (16,384)
// dyn     fp32 [B*C*25]           @ 16,384     (409,600)
// gx2     fp32 [B*CE]             @ 425,984    (65,536)
// scale   fp32 [B*CE]             @ 491,520    (65,536)
// sb      fp32 [C]                @ 557,056    (512)
// y       bf16 [B*C*HW]           @ 557,568    (25,690,112)
// e       bf16 [B*CE*HW]          @ 26,247,680 (102,760,448)
// total: 129,008,128 bytes

__device__ __forceinline__ float wave_reduce_sum(float v) {
#pragma unroll
  for (int off = 32; off > 0; off >>= 1) v += __shfl_down(v, off, 64);
  return v;
}

// ---------------- K1: global average pool ----------------
__global__ __launch_bounds__(256) void pool_kernel(const float* __restrict__ x,
                                                   float* __restrict__ pooled) {
  int bc = blockIdx.x;
  const float* xp = x + (size_t)bc * HW_;
  float s = 0.f;
  for (int i = threadIdx.x; i < HW_; i += 256) s += xp[i];
  s = wave_reduce_sum(s);
  __shared__ float red[4];
  int lane = threadIdx.x & 63, wid = threadIdx.x >> 6;
  if (lane == 0) red[wid] = s;
  __syncthreads();
  if (threadIdx.x == 0) pooled[bc] = (red[0] + red[1] + red[2] + red[3]) * (1.0f / HW_);
}

// ---------------- K2: fc1 -> LN1 -> fc2 (dyn weights) ----------------
__global__ __launch_bounds__(256) void fc_kernel(const float* __restrict__ pooled,
                                                 const float* __restrict__ w_fc1,
                                                 const float* __restrict__ ln1_w,
                                                 const float* __restrict__ ln1_b,
                                                 const float* __restrict__ w_fc2,
                                                 float* __restrict__ dyn) {
  int b = blockIdx.x;
  int tid = threadIdx.x;
  __shared__ float sp[C_];
  __shared__ float sh[CR_];
  __shared__ float shn[CR_];
  __shared__ float stats[2];
  if (tid < C_) sp[tid] = pooled[b * C_ + tid];
  __syncthreads();
  if (tid < CR_) {
    float acc = 0.f;
    const float* wr = w_fc1 + tid * C_;
#pragma unroll 4
    for (int c = 0; c < C_; ++c) acc += sp[c] * wr[c];
    sh[tid] = acc;
  }
  __syncthreads();
  if (tid == 0) {
    float u = 0.f;
    for (int j = 0; j < CR_; ++j) u += sh[j];
    u *= (1.0f / CR_);
    float v = 0.f;
    for (int j = 0; j < CR_; ++j) { float d = sh[j] - u; v += d * d; }
    v *= (1.0f / CR_);
    stats[0] = u;
    stats[1] = rsqrtf(v + EPS_);
  }
  __syncthreads();
  if (tid < CR_) shn[tid] = (sh[tid] - stats[0]) * stats[1] * ln1_w[tid] + ln1_b[tid];
  __syncthreads();
  for (int i = tid; i < C_ * KK_; i += 256) {
    const float* wr = w_fc2 + i * CR_;
    float acc = 0.f;
#pragma unroll
    for (int j = 0; j < CR_; ++j) acc += shn[j] * wr[j];
    dyn[b * (C_ * KK_) + i] = acc;
  }
}

// ---------------- K3: dynamic depthwise 5x5 conv + channel LN -> y (bf16) ----------------
// one block per (b,h); thread = (cq in [0,4)) x (wq in [0,64)); each thread does 32 channels
__global__ __launch_bounds__(256) void conv_ln_kernel(const float* __restrict__ x,
                                                      const float* __restrict__ dyn,
                                                      const float* __restrict__ ln2_w,
                                                      const float* __restrict__ ln2_b,
                                                      bf16* __restrict__ y) {
  int bh = blockIdx.x;
  int b = bh / H_;
  int h = bh % H_;
  int tid = threadIdx.x;
  int wq = tid & 63;
  int cq = tid >> 6;
  __shared__ float wk[C_ * KK_];     // 12.8 KB
  __shared__ float vals[C_][64];     // 32 KB
  __shared__ float redS[4][64];
  __shared__ float redQ[4][64];
  __shared__ float meanArr[64];
  __shared__ float invArr[64];
  for (int i = tid; i < C_ * KK_; i += 256) wk[i] = dyn[b * (C_ * KK_) + i];
  __syncthreads();
  bool active = (wq < W_);
  float ls = 0.f, lq = 0.f;
  for (int k = 0; k < 32; ++k) {
    int c = cq * 32 + k;
    float acc = 0.f;
    if (active) {
      const float* xp = x + ((size_t)(b * C_ + c)) * HW_;
      const float* wp = &wk[c * KK_];
#pragma unroll
      for (int dh = 0; dh < K5_; ++dh) {
        int hh = h + dh - 2;
        if (hh < 0 || hh >= H_) continue;
        const float* row = xp + hh * W_;
#pragma unroll
        for (int dw = 0; dw < K5_; ++dw) {
          int ww = wq + dw - 2;
          if (ww >= 0 && ww < W_) acc += row[ww] * wp[dh * K5_ + dw];
        }
      }
    }
    vals[c][wq] = acc;
    ls += acc;
    lq += acc * acc;
  }
  redS[cq][wq] = ls;
  redQ[cq][wq] = lq;
  __syncthreads();
  if (cq == 0) {
    float s = redS[0][wq] + redS[1][wq] + redS[2][wq] + redS[3][wq];
    float q = redQ[0][wq] + redQ[1][wq] + redQ[2][wq] + redQ[3][wq];
    float m = s * (1.0f / C_);
    float var = q * (1.0f / C_) - m * m;
    meanArr[wq] = m;
    invArr[wq] = rsqrtf(fmaxf(var, 0.f) + EPS_);
  }
  __syncthreads();
  if (active) {
    float m = meanArr[wq], iv = invArr[wq];
    for (int k = 0; k < 32; ++k) {
      int c = cq * 32 + k;
      float yv = (vals[c][wq] - m) * iv * ln2_w[c] + ln2_b[c];
      y[((size_t)(b * C_ + c)) * HW_ + h * W_ + wq] = __float2bfloat16(yv);
    }
  }
}

// ---------------- K4: expand GEMM (512x128 @ 128xHW) + exact GELU + gx2 partials ----------------
// grid (49 s-tiles, 8 o-tiles, B); 64x64 tile, 4x4 per thread
__global__ __launch_bounds__(256) void expand_kernel(const bf16* __restrict__ y,
                                                     const float* __restrict__ w_expand,
                                                     bf16* __restrict__ e,
                                                     float* __restrict__ gx2) {
  int s0 = blockIdx.x * 64;
  int o0 = blockIdx.y * 64;
  int b = blockIdx.z;
  int tid = threadIdx.x;
  int tx = tid & 15;   // s group
  int ty = tid >> 4;   // o group
  __shared__ float ys[16][64];    // [k][s]
  __shared__ float weT[16][68];   // [k][o], padded: b128-aligned reads, 2-way writes
  float acc[4][4] = {};
  for (int c0 = 0; c0 < C_; c0 += 16) {
    {  // y tile: ushort4 vector loads, 4 bf16 each
      int id = tid * 4;
      int kk = id >> 6, ss = id & 63;
      const unsigned short* yp =
          reinterpret_cast<const unsigned short*>(y) + ((size_t)(b * C_ + c0 + kk)) * HW_ + s0 + ss;
      ushort4 uv = *reinterpret_cast<const ushort4*>(yp);
      ys[kk][ss + 0] = __uint_as_float(((unsigned)uv.x) << 16);
      ys[kk][ss + 1] = __uint_as_float(((unsigned)uv.y) << 16);
      ys[kk][ss + 2] = __uint_as_float(((unsigned)uv.z) << 16);
      ys[kk][ss + 3] = __uint_as_float(((unsigned)uv.w) << 16);
    }
#pragma unroll
    for (int r = 0; r < 4; ++r) {  // w_expand tile (transposed into LDS)
      int id = tid + r * 256;
      int kk = id & 15, oo = id >> 4;
      weT[kk][oo] = w_expand[(size_t)(o0 + oo) * C_ + c0 + kk];
    }
    __syncthreads();
#pragma unroll
    for (int kk = 0; kk < 16; ++kk) {
      float4 av = *reinterpret_cast<const float4*>(&weT[kk][ty * 4]);
      float4 bv = *reinterpret_cast<const float4*>(&ys[kk][tx * 4]);
      acc[0][0] += av.x * bv.x; acc[0][1] += av.x * bv.y; acc[0][2] += av.x * bv.z; acc[0][3] += av.x * bv.w;
      acc[1][0] += av.y * bv.x; acc[1][1] += av.y * bv.y; acc[1][2] += av.y * bv.z; acc[1][3] += av.y * bv.w;
      acc[2][0] += av.z * bv.x; acc[2][1] += av.z * bv.y; acc[2][2] += av.z * bv.z; acc[2][3] += av.z * bv.w;
      acc[3][0] += av.w * bv.x; acc[3][1] += av.w * bv.y; acc[3][2] += av.w * bv.z; acc[3][3] += av.w * bv.w;
    }
    __syncthreads();
  }
  float gsum[4];
#pragma unroll
  for (int i = 0; i < 4; ++i) {
    int o = o0 + ty * 4 + i;
    size_t base = ((size_t)(b * CE_ + o)) * HW_ + s0 + tx * 4;
    unsigned short pk[4];
    float gs = 0.f;
#pragma unroll
    for (int j = 0; j < 4; ++j) {
      float v = acc[i][j];
      float ge = 0.5f * v * (1.0f + erff(v * 0.7071067811865475f));
      gs += ge * ge;
      bf16 hb = __float2bfloat16(ge);
      __builtin_memcpy(&pk[j], &hb, 2);
    }
    gsum[i] = gs;
    *reinterpret_cast<ushort4*>(reinterpret_cast<unsigned short*>(e) + base) =
        make_ushort4(pk[0], pk[1], pk[2], pk[3]);
  }
#pragma unroll
  for (int i = 0; i < 4; ++i) {  // reduce over the 16 tx lanes (adjacent within the wave)
    float g = gsum[i];
#pragma unroll
    for (int off = 8; off > 0; off >>= 1) g += __shfl_xor(g, off, 16);
    if (tx == 0) atomicAdd(&gx2[b * CE_ + o0 + ty * 4 + i], g);
  }
}

// ---------------- K5a: GRN per-batch scale ----------------
__global__ __launch_bounds__(512) void grn_scale_kernel(const float* __restrict__ gx2,
                                                        const float* __restrict__ gamma,
                                                        float* __restrict__ scale) {
  int b = blockIdx.x;
  int o = threadIdx.x;  // 512 threads
  float gx = sqrtf(gx2[b * CE_ + o]);
  float s = wave_reduce_sum(gx);
  __shared__ float red[8];
  __shared__ float meansh;
  int lane = o & 63, wid = o >> 6;
  if (lane == 0) red[wid] = s;
  __syncthreads();
  if (o == 0) {
    float t = 0.f;
    for (int i = 0; i < 8; ++i) t += red[i];
    meansh = t * (1.0f / CE_);
  }
  __syncthreads();
  scale[b * CE_ + o] = 1.0f + gamma[o] * (gx / (meansh + EPS_));
}

// ---------------- K5b: sb[c] = sum_o w_shrink[c,o] * beta[o] ----------------
__global__ __launch_bounds__(128) void sb_kernel(const float* __restrict__ w_shrink,
                                                 const float* __restrict__ beta,
                                                 float* __restrict__ sb) {
  int c = threadIdx.x;
  float acc = 0.f;
  for (int o = 0; o < CE_; ++o) acc += w_shrink[c * CE_ + o] * beta[o];
  sb[c] = acc;
}

// ---------------- K6: shrink GEMM with per-batch rescaled weights + bias + residual ----------------
// grid (98 s-tiles, B); tile C=128 x S=32, 4x4 per thread
__global__ __launch_bounds__(256) void shrink_kernel(const bf16* __restrict__ e,
                                                     const float* __restrict__ w_shrink,
                                                     const float* __restrict__ scale,
                                                     const float* __restrict__ sb,
                                                     const float* __restrict__ x,
                                                     float* __restrict__ out) {
  int s0 = blockIdx.x * 32;
  int b = blockIdx.y;
  int tid = threadIdx.x;
  int tx = tid & 7;   // s group (8*4 = 32)
  int ty = tid >> 3;  // c group (32*4 = 128)
  __shared__ float es[16][32];     // [k][s]
  __shared__ float w2T[16][132];   // [k][c], padded
  float acc[4][4] = {};
  for (int o0 = 0; o0 < CE_; o0 += 16) {
    {  // e tile: ushort2 loads (2 bf16 per thread)
      int id = tid * 2;
      int kk = id >> 5, ss = id & 31;
      const unsigned short* ep =
          reinterpret_cast<const unsigned short*>(e) + ((size_t)(b * CE_ + o0 + kk)) * HW_ + s0 + ss;
      ushort2 uv = *reinterpret_cast<const ushort2*>(ep);
      es[kk][ss + 0] = __uint_as_float(((unsigned)uv.x) << 16);
      es[kk][ss + 1] = __uint_as_float(((unsigned)uv.y) << 16);
    }
#pragma unroll
    for (int r = 0; r < 8; ++r) {  // w_shrink tile * scale, transposed
      int id = tid + r * 256;
      int kk = id & 15, cc = id >> 4;
      w2T[kk][cc] = w_shrink[(size_t)cc * CE_ + o0 + kk] * scale[b * CE_ + o0 + kk];
    }
    __syncthreads();
#pragma unroll
    for (int kk = 0; kk < 16; ++kk) {
      float4 av = *reinterpret_cast<const float4*>(&w2T[kk][ty * 4]);
      float4 bv = *reinterpret_cast<const float4*>(&es[kk][tx * 4]);
      acc[0][0] += av.x * bv.x; acc[0][1] += av.x * bv.y; acc[0][2] += av.x * bv.z; acc[0][3] += av.x * bv.w;
      acc[1][0] += av.y * bv.x; acc[1][1] += av.y * bv.y; acc[1][2] += av.y * bv.z; acc[1][3] += av.y * bv.w;
      acc[2][0] += av.z * bv.x; acc[2][1] += av.z * bv.y; acc[2][2] += av.z * bv.z; acc[2][3] += av.z * bv.w;
      acc[3][0] += av.w * bv.x; acc[3][1] += av.w * bv.y; acc[3][2] += av.w * bv.z; acc[3][3] += av.w * bv.w;
    }
    __syncthreads();
  }
#pragma unroll
  for (int i = 0; i < 4; ++i) {
    int c = ty * 4 + i;
    size_t base = ((size_t)(b * C_ + c)) * HW_ + s0 + tx * 4;
    float add = sb[c];
    float4 xv = *reinterpret_cast<const float4*>(x + base);
    float4 ov;
    ov.x = acc[i][0] + add + xv.x;
    ov.y = acc[i][1] + add + xv.y;
    ov.z = acc[i][2] + add + xv.z;
    ov.w = acc[i][3] + add + xv.w;
    *reinterpret_cast<float4*>(out + base) = ov;
  }
}

extern "C" void kernel_launch(void* const* d_in, const int* in_sizes, int n_in,
                              void* d_out, int out_size, void* d_ws, size_t ws_size,
                              hipStream_t stream) {
  (void)in_sizes; (void)n_in; (void)out_size; (void)ws_size;
  const float* x        = (const float*)d_in[0];
  const float* w_fc1    = (const float*)d_in[1];
  const float* ln1_w    = (const float*)d_in[2];
  const float* ln1_b    = (const float*)d_in[3];
  const float* w_fc2    = (const float*)d_in[4];
  const float* ln2_w    = (const float*)d_in[5];
  const float* ln2_b    = (const float*)d_in[6];
  const float* w_expand = (const float*)d_in[7];
  const float* w_shrink = (const float*)d_in[8];
  const float* gamma    = (const float*)d_in[9];
  const float* beta     = (const float*)d_in[10];
  float* out = (float*)d_out;

  char* ws = (char*)d_ws;
  float* pooled = (float*)(ws + 0);
  float* dyn    = (float*)(ws + 16384);
  float* gx2    = (float*)(ws + 425984);
  float* scale  = (float*)(ws + 491520);
  float* sb     = (float*)(ws + 557056);
  bf16*  y      = (bf16*)(ws + 557568);
  bf16*  e      = (bf16*)(ws + 26247680);

  pool_kernel<<<B_ * C_, 256, 0, stream>>>(x, pooled);
  fc_kernel<<<B_, 256, 0, stream>>>(pooled, w_fc1, ln1_w, ln1_b, w_fc2, dyn);
  conv_ln_kernel<<<B_ * H_, 256, 0, stream>>>(x, dyn, ln2_w, ln2_b, y);
  hipMemsetAsync(gx2, 0, B_ * CE_ * sizeof(float), stream);
  expand_kernel<<<dim3(49, 8, B_), 256, 0, stream>>>(y, w_expand, e, gx2);
  grn_scale_kernel<<<B_, 512, 0, stream>>>(gx2, gamma, scale);
  sb_kernel<<<1, 128, 0, stream>>>(w_shrink, beta, sb);
  shrink_kernel<<<dim3(98, B_), 256, 0, stream>>>(e, w_shrink, scale, sb, x, out);
}

// Round 2
// 606.543 us; speedup vs baseline: 1.5844x; 1.5844x over previous
//
#include <hip/hip_runtime.h>
#include <hip/hip_bf16.h>

#define B_   32
#define C_   128
#define H_   56
#define W_   56
#define HW_  (H_*W_)
#define K5_  5
#define KK_  25
#define CR_  32
#define CE_  512
#define EPS_ 1e-6f

typedef __hip_bfloat16 bf16;

// ---------- workspace layout (bytes) ----------
// pooled  fp32 [B*C]              @ 0          (16,384)
// dyn     fp32 [B*C*25]           @ 16,384     (409,600)
// gx2     fp32 [B*CE]             @ 425,984    (65,536)
// scale   fp32 [B*CE]             @ 491,520    (65,536)
// sb      fp32 [C]                @ 557,056    (512)
// y       bf16 [B*C*HW]           @ 557,568    (25,690,112)
// e       bf16 [B*CE*HW]          @ 26,247,680 (102,760,448)
//   z (bf16 [B*C*HW], conv output pre-LN) ALIASES the head of e:
//   z dead once ln_kernel finishes; expand overwrites e afterwards.
// total: 129,008,128 bytes (unchanged from round 1)

__device__ __forceinline__ float wave_reduce_sum(float v) {
#pragma unroll
  for (int off = 32; off > 0; off >>= 1) v += __shfl_down(v, off, 64);
  return v;
}

__device__ __forceinline__ float bf2f(unsigned short u) {
  return __uint_as_float(((unsigned)u) << 16);
}
__device__ __forceinline__ unsigned short f2bf_bits(float f) {
  bf16 h = __float2bfloat16(f);
  unsigned short u;
  __builtin_memcpy(&u, &h, 2);
  return u;
}

// ---------------- K1: global average pool ----------------
__global__ __launch_bounds__(256) void pool_kernel(const float* __restrict__ x,
                                                   float* __restrict__ pooled) {
  int bc = blockIdx.x;
  const float* xp = x + (size_t)bc * HW_;
  float s = 0.f;
  for (int i = threadIdx.x; i < HW_; i += 256) s += xp[i];
  s = wave_reduce_sum(s);
  __shared__ float red[4];
  int lane = threadIdx.x & 63, wid = threadIdx.x >> 6;
  if (lane == 0) red[wid] = s;
  __syncthreads();
  if (threadIdx.x == 0) pooled[bc] = (red[0] + red[1] + red[2] + red[3]) * (1.0f / HW_);
}

// ---------------- K2: fc1 -> LN1 -> fc2 (dyn weights) ----------------
__global__ __launch_bounds__(256) void fc_kernel(const float* __restrict__ pooled,
                                                 const float* __restrict__ w_fc1,
                                                 const float* __restrict__ ln1_w,
                                                 const float* __restrict__ ln1_b,
                                                 const float* __restrict__ w_fc2,
                                                 float* __restrict__ dyn) {
  int b = blockIdx.x;
  int tid = threadIdx.x;
  __shared__ float sp[C_];
  __shared__ float sh[CR_];
  __shared__ float shn[CR_];
  __shared__ float stats[2];
  if (tid < C_) sp[tid] = pooled[b * C_ + tid];
  __syncthreads();
  if (tid < CR_) {
    float acc = 0.f;
    const float* wr = w_fc1 + tid * C_;
#pragma unroll 4
    for (int c = 0; c < C_; ++c) acc += sp[c] * wr[c];
    sh[tid] = acc;
  }
  __syncthreads();
  if (tid == 0) {
    float u = 0.f;
    for (int j = 0; j < CR_; ++j) u += sh[j];
    u *= (1.0f / CR_);
    float v = 0.f;
    for (int j = 0; j < CR_; ++j) { float d = sh[j] - u; v += d * d; }
    v *= (1.0f / CR_);
    stats[0] = u;
    stats[1] = rsqrtf(v + EPS_);
  }
  __syncthreads();
  if (tid < CR_) shn[tid] = (sh[tid] - stats[0]) * stats[1] * ln1_w[tid] + ln1_b[tid];
  __syncthreads();
  for (int i = tid; i < C_ * KK_; i += 256) {
    const float* wr = w_fc2 + i * CR_;
    float acc = 0.f;
#pragma unroll
    for (int j = 0; j < CR_; ++j) acc += shn[j] * wr[j];
    dyn[b * (C_ * KK_) + i] = acc;
  }
}

// ---------------- K3a: dynamic depthwise 5x5 conv -> z (bf16) ----------------
// one block per (b,c); full 56x56 channel staged in LDS with zero-padded halo
// columns (row stride 64, data at cols 2..57). Each thread computes groups of
// 4 horizontal pixels: two ds_read_b128 per tap-row instead of 25 scalar
// global loads per pixel.
__global__ __launch_bounds__(256) void conv_kernel(const float* __restrict__ x,
                                                   const float* __restrict__ dyn,
                                                   bf16* __restrict__ z) {
  int bc = blockIdx.x;          // b*C + c
  int b = bc >> 7;
  int c = bc & 127;
  int tid = threadIdx.x;
  __shared__ float xs[H_ * 64];   // 14,336 B
  __shared__ float wks[KK_];
  // zero the halo columns 0,1,58,59 (cols 60..63 never read)
  if (tid < H_ * 4) {
    int r = tid >> 2, q = tid & 3;
    int col = (q < 2) ? q : (56 + q);
    xs[r * 64 + col] = 0.f;
  }
  if (tid < KK_) wks[tid] = dyn[b * (C_ * KK_) + c * KK_ + tid];
  // stage the channel: 784 float4 loads, scattered into padded rows
  const float4* xp4 = reinterpret_cast<const float4*>(x + (size_t)bc * HW_);
  for (int i = tid; i < 784; i += 256) {
    float4 v = xp4[i];
    int h = i / 14, w4 = (i % 14) * 4;
    float* dst = &xs[h * 64 + 2 + w4];
    dst[0] = v.x; dst[1] = v.y; dst[2] = v.z; dst[3] = v.w;
  }
  __syncthreads();
  float wr[KK_];
#pragma unroll
  for (int j = 0; j < KK_; ++j) wr[j] = wks[j];

  for (int g = tid; g < 784; g += 256) {
    int h = g / 14;
    int w4 = (g % 14) * 4;
    float a0 = 0.f, a1 = 0.f, a2 = 0.f, a3 = 0.f;
#pragma unroll
    for (int dh = 0; dh < K5_; ++dh) {
      int hh = h + dh - 2;
      if (hh < 0 || hh >= H_) continue;
      const float* row = &xs[hh * 64 + w4];  // = x[hh][w4-2 ...]
      float4 va = *reinterpret_cast<const float4*>(row);
      float4 vb = *reinterpret_cast<const float4*>(row + 4);
      float v0 = va.x, v1 = va.y, v2 = va.z, v3 = va.w;
      float v4 = vb.x, v5 = vb.y, v6 = vb.z, v7 = vb.w;
      float u0 = wr[dh * 5 + 0], u1 = wr[dh * 5 + 1], u2 = wr[dh * 5 + 2];
      float u3 = wr[dh * 5 + 3], u4 = wr[dh * 5 + 4];
      a0 += v0 * u0 + v1 * u1 + v2 * u2 + v3 * u3 + v4 * u4;
      a1 += v1 * u0 + v2 * u1 + v3 * u2 + v4 * u3 + v5 * u4;
      a2 += v2 * u0 + v3 * u1 + v4 * u2 + v5 * u3 + v6 * u4;
      a3 += v3 * u0 + v4 * u1 + v5 * u2 + v6 * u3 + v7 * u4;
    }
    size_t base = (size_t)bc * HW_ + h * W_ + w4;
    ushort4 pk = make_ushort4(f2bf_bits(a0), f2bf_bits(a1), f2bf_bits(a2), f2bf_bits(a3));
    *reinterpret_cast<ushort4*>(reinterpret_cast<unsigned short*>(z) + base) = pk;
  }
}

// ---------------- K3b: channel LN over z -> y (bf16) ----------------
// grid (49 hw-tiles, B); threads 256 = 4 c-groups x 64 hw; z tile staged in LDS
__global__ __launch_bounds__(256) void ln_kernel(const bf16* __restrict__ z,
                                                 const float* __restrict__ ln2_w,
                                                 const float* __restrict__ ln2_b,
                                                 bf16* __restrict__ y) {
  int hw0 = blockIdx.x * 64;
  int b = blockIdx.y;
  int tid = threadIdx.x;
  int wq = tid & 63;
  int cq = tid >> 6;
  __shared__ unsigned short zt[C_][64];   // 16 KB
  __shared__ float redS[4][64];
  __shared__ float redQ[4][64];
  __shared__ float meanArr[64];
  __shared__ float invArr[64];
  float s = 0.f, q = 0.f;
  const unsigned short* zp = reinterpret_cast<const unsigned short*>(z);
#pragma unroll 4
  for (int k = 0; k < 32; ++k) {
    int c = cq * 32 + k;
    unsigned short u = zp[((size_t)(b * C_ + c)) * HW_ + hw0 + wq];
    float v = bf2f(u);
    s += v;
    q += v * v;
    zt[c][wq] = u;
  }
  redS[cq][wq] = s;
  redQ[cq][wq] = q;
  __syncthreads();
  if (cq == 0) {
    float ss = redS[0][wq] + redS[1][wq] + redS[2][wq] + redS[3][wq];
    float qq = redQ[0][wq] + redQ[1][wq] + redQ[2][wq] + redQ[3][wq];
    float m = ss * (1.0f / C_);
    float var = qq * (1.0f / C_) - m * m;
    meanArr[wq] = m;
    invArr[wq] = rsqrtf(fmaxf(var, 0.f) + EPS_);
  }
  __syncthreads();
  float m = meanArr[wq], iv = invArr[wq];
  unsigned short* yp = reinterpret_cast<unsigned short*>(y);
#pragma unroll 4
  for (int k = 0; k < 32; ++k) {
    int c = cq * 32 + k;
    float v = bf2f(zt[c][wq]);
    float yv = (v - m) * iv * ln2_w[c] + ln2_b[c];
    yp[((size_t)(b * C_ + c)) * HW_ + hw0 + wq] = f2bf_bits(yv);
  }
}

// ---------------- K4: expand GEMM (512x128 @ 128xHW) + exact GELU + gx2 partials ----------------
__global__ __launch_bounds__(256) void expand_kernel(const bf16* __restrict__ y,
                                                     const float* __restrict__ w_expand,
                                                     bf16* __restrict__ e,
                                                     float* __restrict__ gx2) {
  int s0 = blockIdx.x * 64;
  int o0 = blockIdx.y * 64;
  int b = blockIdx.z;
  int tid = threadIdx.x;
  int tx = tid & 15;   // s group
  int ty = tid >> 4;   // o group
  __shared__ float ys[16][64];    // [k][s]
  __shared__ float weT[16][68];   // [k][o], padded
  float acc[4][4] = {};
  for (int c0 = 0; c0 < C_; c0 += 16) {
    {
      int id = tid * 4;
      int kk = id >> 6, ss = id & 63;
      const unsigned short* yp =
          reinterpret_cast<const unsigned short*>(y) + ((size_t)(b * C_ + c0 + kk)) * HW_ + s0 + ss;
      ushort4 uv = *reinterpret_cast<const ushort4*>(yp);
      ys[kk][ss + 0] = bf2f(uv.x);
      ys[kk][ss + 1] = bf2f(uv.y);
      ys[kk][ss + 2] = bf2f(uv.z);
      ys[kk][ss + 3] = bf2f(uv.w);
    }
#pragma unroll
    for (int r = 0; r < 4; ++r) {
      int id = tid + r * 256;
      int kk = id & 15, oo = id >> 4;
      weT[kk][oo] = w_expand[(size_t)(o0 + oo) * C_ + c0 + kk];
    }
    __syncthreads();
#pragma unroll
    for (int kk = 0; kk < 16; ++kk) {
      float4 av = *reinterpret_cast<const float4*>(&weT[kk][ty * 4]);
      float4 bv = *reinterpret_cast<const float4*>(&ys[kk][tx * 4]);
      acc[0][0] += av.x * bv.x; acc[0][1] += av.x * bv.y; acc[0][2] += av.x * bv.z; acc[0][3] += av.x * bv.w;
      acc[1][0] += av.y * bv.x; acc[1][1] += av.y * bv.y; acc[1][2] += av.y * bv.z; acc[1][3] += av.y * bv.w;
      acc[2][0] += av.z * bv.x; acc[2][1] += av.z * bv.y; acc[2][2] += av.z * bv.z; acc[2][3] += av.z * bv.w;
      acc[3][0] += av.w * bv.x; acc[3][1] += av.w * bv.y; acc[3][2] += av.w * bv.z; acc[3][3] += av.w * bv.w;
    }
    __syncthreads();
  }
  float gsum[4];
#pragma unroll
  for (int i = 0; i < 4; ++i) {
    int o = o0 + ty * 4 + i;
    size_t base = ((size_t)(b * CE_ + o)) * HW_ + s0 + tx * 4;
    unsigned short pk[4];
    float gs = 0.f;
#pragma unroll
    for (int j = 0; j < 4; ++j) {
      float v = acc[i][j];
      float ge = 0.5f * v * (1.0f + erff(v * 0.7071067811865475f));
      gs += ge * ge;
      pk[j] = f2bf_bits(ge);
    }
    gsum[i] = gs;
    *reinterpret_cast<ushort4*>(reinterpret_cast<unsigned short*>(e) + base) =
        make_ushort4(pk[0], pk[1], pk[2], pk[3]);
  }
#pragma unroll
  for (int i = 0; i < 4; ++i) {
    float g = gsum[i];
#pragma unroll
    for (int off = 8; off > 0; off >>= 1) g += __shfl_xor(g, off, 16);
    if (tx == 0) atomicAdd(&gx2[b * CE_ + o0 + ty * 4 + i], g);
  }
}

// ---------------- K5a: GRN per-batch scale ----------------
__global__ __launch_bounds__(512) void grn_scale_kernel(const float* __restrict__ gx2,
                                                        const float* __restrict__ gamma,
                                                        float* __restrict__ scale) {
  int b = blockIdx.x;
  int o = threadIdx.x;
  float gx = sqrtf(gx2[b * CE_ + o]);
  float s = wave_reduce_sum(gx);
  __shared__ float red[8];
  __shared__ float meansh;
  int lane = o & 63, wid = o >> 6;
  if (lane == 0) red[wid] = s;
  __syncthreads();
  if (o == 0) {
    float t = 0.f;
    for (int i = 0; i < 8; ++i) t += red[i];
    meansh = t * (1.0f / CE_);
  }
  __syncthreads();
  scale[b * CE_ + o] = 1.0f + gamma[o] * (gx / (meansh + EPS_));
}

// ---------------- K5b: sb[c] = sum_o w_shrink[c,o] * beta[o] ----------------
__global__ __launch_bounds__(128) void sb_kernel(const float* __restrict__ w_shrink,
                                                 const float* __restrict__ beta,
                                                 float* __restrict__ sb) {
  int c = threadIdx.x;
  float acc = 0.f;
  for (int o = 0; o < CE_; ++o) acc += w_shrink[c * CE_ + o] * beta[o];
  sb[c] = acc;
}

// ---------------- K6: shrink GEMM with per-batch rescaled weights + bias + residual ----------------
__global__ __launch_bounds__(256) void shrink_kernel(const bf16* __restrict__ e,
                                                     const float* __restrict__ w_shrink,
                                                     const float* __restrict__ scale,
                                                     const float* __restrict__ sb,
                                                     const float* __restrict__ x,
                                                     float* __restrict__ out) {
  int s0 = blockIdx.x * 32;
  int b = blockIdx.y;
  int tid = threadIdx.x;
  int tx = tid & 7;
  int ty = tid >> 3;
  __shared__ float es[16][32];
  __shared__ float w2T[16][132];
  float acc[4][4] = {};
  for (int o0 = 0; o0 < CE_; o0 += 16) {
    {
      int id = tid * 2;
      int kk = id >> 5, ss = id & 31;
      const unsigned short* ep =
          reinterpret_cast<const unsigned short*>(e) + ((size_t)(b * CE_ + o0 + kk)) * HW_ + s0 + ss;
      ushort2 uv = *reinterpret_cast<const ushort2*>(ep);
      es[kk][ss + 0] = bf2f(uv.x);
      es[kk][ss + 1] = bf2f(uv.y);
    }
#pragma unroll
    for (int r = 0; r < 8; ++r) {
      int id = tid + r * 256;
      int kk = id & 15, cc = id >> 4;
      w2T[kk][cc] = w_shrink[(size_t)cc * CE_ + o0 + kk] * scale[b * CE_ + o0 + kk];
    }
    __syncthreads();
#pragma unroll
    for (int kk = 0; kk < 16; ++kk) {
      float4 av = *reinterpret_cast<const float4*>(&w2T[kk][ty * 4]);
      float4 bv = *reinterpret_cast<const float4*>(&es[kk][tx * 4]);
      acc[0][0] += av.x * bv.x; acc[0][1] += av.x * bv.y; acc[0][2] += av.x * bv.z; acc[0][3] += av.x * bv.w;
      acc[1][0] += av.y * bv.x; acc[1][1] += av.y * bv.y; acc[1][2] += av.y * bv.z; acc[1][3] += av.y * bv.w;
      acc[2][0] += av.z * bv.x; acc[2][1] += av.z * bv.y; acc[2][2] += av.z * bv.z; acc[2][3] += av.z * bv.w;
      acc[3][0] += av.w * bv.x; acc[3][1] += av.w * bv.y; acc[3][2] += av.w * bv.z; acc[3][3] += av.w * bv.w;
    }
    __syncthreads();
  }
#pragma unroll
  for (int i = 0; i < 4; ++i) {
    int c = ty * 4 + i;
    size_t base = ((size_t)(b * C_ + c)) * HW_ + s0 + tx * 4;
    float add = sb[c];
    float4 xv = *reinterpret_cast<const float4*>(x + base);
    float4 ov;
    ov.x = acc[i][0] + add + xv.x;
    ov.y = acc[i][1] + add + xv.y;
    ov.z = acc[i][2] + add + xv.z;
    ov.w = acc[i][3] + add + xv.w;
    *reinterpret_cast<float4*>(out + base) = ov;
  }
}

extern "C" void kernel_launch(void* const* d_in, const int* in_sizes, int n_in,
                              void* d_out, int out_size, void* d_ws, size_t ws_size,
                              hipStream_t stream) {
  (void)in_sizes; (void)n_in; (void)out_size; (void)ws_size;
  const float* x        = (const float*)d_in[0];
  const float* w_fc1    = (const float*)d_in[1];
  const float* ln1_w    = (const float*)d_in[2];
  const float* ln1_b    = (const float*)d_in[3];
  const float* w_fc2    = (const float*)d_in[4];
  const float* ln2_w    = (const float*)d_in[5];
  const float* ln2_b    = (const float*)d_in[6];
  const float* w_expand = (const float*)d_in[7];
  const float* w_shrink = (const float*)d_in[8];
  const float* gamma    = (const float*)d_in[9];
  const float* beta     = (const float*)d_in[10];
  float* out = (float*)d_out;

  char* ws = (char*)d_ws;
  float* pooled = (float*)(ws + 0);
  float* dyn    = (float*)(ws + 16384);
  float* gx2    = (float*)(ws + 425984);
  float* scale  = (float*)(ws + 491520);
  float* sb     = (float*)(ws + 557056);
  bf16*  y      = (bf16*)(ws + 557568);
  bf16*  e      = (bf16*)(ws + 26247680);
  bf16*  z      = e;  // alias: z is dead before expand_kernel writes e

  pool_kernel<<<B_ * C_, 256, 0, stream>>>(x, pooled);
  fc_kernel<<<B_, 256, 0, stream>>>(pooled, w_fc1, ln1_w, ln1_b, w_fc2, dyn);
  conv_kernel<<<B_ * C_, 256, 0, stream>>>(x, dyn, z);
  ln_kernel<<<dim3(49, B_), 256, 0, stream>>>(z, ln2_w, ln2_b, y);
  hipMemsetAsync(gx2, 0, B_ * CE_ * sizeof(float), stream);
  expand_kernel<<<dim3(49, 8, B_), 256, 0, stream>>>(y, w_expand, e, gx2);
  grn_scale_kernel<<<B_, 512, 0, stream>>>(gx2, gamma, scale);
  sb_kernel<<<1, 128, 0, stream>>>(w_shrink, beta, sb);
  shrink_kernel<<<dim3(98, B_), 256, 0, stream>>>(e, w_shrink, scale, sb, x, out);
}

// Round 3
// 316.336 us; speedup vs baseline: 3.0380x; 1.9174x over previous
//
#include <hip/hip_runtime.h>
#include <hip/hip_bf16.h>

#define B_   32
#define C_   128
#define H_   56
#define W_   56
#define HW_  (H_*W_)
#define BHW_ (B_*HW_)        // 100352 = 784*128; 3136 = 196*16 (b-boundaries 16-aligned)
#define K5_  5
#define KK_  25
#define CR_  32
#define CE_  512
#define EPS_ 1e-6f

typedef __hip_bfloat16 bf16;
typedef __attribute__((ext_vector_type(8))) short short8;   // 8 bf16 (4 VGPRs)
typedef __attribute__((ext_vector_type(4))) float f32x4;

// ---------- workspace layout (bytes) ----------
// pooled fp32 [B*C]        @ 0         (16,384)
// dyn    fp32 [B*C*25]     @ 16,384    (409,600)
// gx2    fp32 [B*CE]       @ 425,984   (65,536)
// scale  fp32 [B*CE]       @ 491,520   (65,536)
// sb     fp32 [C]          @ 557,056   (512)
// weB    bf16 [CE*C]       @ 557,568   (131,072)
// wsB    bf16 [C*CE]       @ 688,640   (131,072)
// yT     bf16 [BHW][C]     @ 819,712   (25,690,112)
// eT     bf16 [BHW][CE]    @ 26,509,824 (102,760,448)  (z aliases head of eT)
// total: 129,270,272 bytes

__device__ __forceinline__ float wave_reduce_sum(float v) {
#pragma unroll
  for (int off = 32; off > 0; off >>= 1) v += __shfl_down(v, off, 64);
  return v;
}
__device__ __forceinline__ float bf2f(unsigned short u) {
  return __uint_as_float(((unsigned)u) << 16);
}
__device__ __forceinline__ unsigned short f2bf_bits(float f) {
  bf16 h = __float2bfloat16(f);
  unsigned short u;
  __builtin_memcpy(&u, &h, 2);
  return u;
}
// tanh-form GELU (~8 VALU ops); |err| vs exact erf-GELU ~1e-3, well under bf16 rounding of e
__device__ __forceinline__ float fast_gelu(float v) {
  float u = 0.7978845608f * v * (1.0f + 0.044715f * v * v);
  float a = fabsf(u);
  float t = __expf(-2.0f * a);
  float th = __builtin_copysignf((1.0f - t) / (1.0f + t), u);
  return 0.5f * v * (1.0f + th);
}

// ---------------- K0: weight bf16 conversion ----------------
__global__ __launch_bounds__(256) void prep_kernel(const float* __restrict__ we,
                                                   const float* __restrict__ ws,
                                                   bf16* __restrict__ weB,
                                                   bf16* __restrict__ wsB) {
  int i = blockIdx.x * 256 + threadIdx.x;   // 65536 elements each
  if (i < CE_ * C_) {
    weB[i] = __float2bfloat16(we[i]);
    wsB[i] = __float2bfloat16(ws[i]);
  }
}

// ---------------- K1: global average pool ----------------
__global__ __launch_bounds__(256) void pool_kernel(const float* __restrict__ x,
                                                   float* __restrict__ pooled) {
  int bc = blockIdx.x;
  const float* xp = x + (size_t)bc * HW_;
  float s = 0.f;
  for (int i = threadIdx.x; i < HW_; i += 256) s += xp[i];
  s = wave_reduce_sum(s);
  __shared__ float red[4];
  int lane = threadIdx.x & 63, wid = threadIdx.x >> 6;
  if (lane == 0) red[wid] = s;
  __syncthreads();
  if (threadIdx.x == 0) pooled[bc] = (red[0] + red[1] + red[2] + red[3]) * (1.0f / HW_);
}

// ---------------- K2: fc1 -> LN1 -> fc2 (dyn weights) ----------------
__global__ __launch_bounds__(256) void fc_kernel(const float* __restrict__ pooled,
                                                 const float* __restrict__ w_fc1,
                                                 const float* __restrict__ ln1_w,
                                                 const float* __restrict__ ln1_b,
                                                 const float* __restrict__ w_fc2,
                                                 float* __restrict__ dyn) {
  int b = blockIdx.x;
  int tid = threadIdx.x;
  __shared__ float sp[C_];
  __shared__ float sh[CR_];
  __shared__ float shn[CR_];
  __shared__ float stats[2];
  if (tid < C_) sp[tid] = pooled[b * C_ + tid];
  __syncthreads();
  if (tid < CR_) {
    float acc = 0.f;
    const float* wr = w_fc1 + tid * C_;
#pragma unroll 4
    for (int c = 0; c < C_; ++c) acc += sp[c] * wr[c];
    sh[tid] = acc;
  }
  __syncthreads();
  if (tid == 0) {
    float u = 0.f;
    for (int j = 0; j < CR_; ++j) u += sh[j];
    u *= (1.0f / CR_);
    float v = 0.f;
    for (int j = 0; j < CR_; ++j) { float d = sh[j] - u; v += d * d; }
    v *= (1.0f / CR_);
    stats[0] = u;
    stats[1] = rsqrtf(v + EPS_);
  }
  __syncthreads();
  if (tid < CR_) shn[tid] = (sh[tid] - stats[0]) * stats[1] * ln1_w[tid] + ln1_b[tid];
  __syncthreads();
  for (int i = tid; i < C_ * KK_; i += 256) {
    const float* wr = w_fc2 + i * CR_;
    float acc = 0.f;
#pragma unroll
    for (int j = 0; j < CR_; ++j) acc += shn[j] * wr[j];
    dyn[b * (C_ * KK_) + i] = acc;
  }
}

// ---------------- K3a: dynamic depthwise 5x5 conv -> z (bf16, [b][c][hw]) ----------------
__global__ __launch_bounds__(256) void conv_kernel(const float* __restrict__ x,
                                                   const float* __restrict__ dyn,
                                                   bf16* __restrict__ z) {
  int bc = blockIdx.x;
  int b = bc >> 7;
  int c = bc & 127;
  int tid = threadIdx.x;
  __shared__ float xs[H_ * 64];
  __shared__ float wks[KK_];
  if (tid < H_ * 4) {
    int r = tid >> 2, q = tid & 3;
    int col = (q < 2) ? q : (56 + q);
    xs[r * 64 + col] = 0.f;
  }
  if (tid < KK_) wks[tid] = dyn[b * (C_ * KK_) + c * KK_ + tid];
  const float4* xp4 = reinterpret_cast<const float4*>(x + (size_t)bc * HW_);
  for (int i = tid; i < 784; i += 256) {
    float4 v = xp4[i];
    int h = i / 14, w4 = (i % 14) * 4;
    float* dst = &xs[h * 64 + 2 + w4];
    dst[0] = v.x; dst[1] = v.y; dst[2] = v.z; dst[3] = v.w;
  }
  __syncthreads();
  float wr[KK_];
#pragma unroll
  for (int j = 0; j < KK_; ++j) wr[j] = wks[j];
  for (int g = tid; g < 784; g += 256) {
    int h = g / 14;
    int w4 = (g % 14) * 4;
    float a0 = 0.f, a1 = 0.f, a2 = 0.f, a3 = 0.f;
#pragma unroll
    for (int dh = 0; dh < K5_; ++dh) {
      int hh = h + dh - 2;
      if (hh < 0 || hh >= H_) continue;
      const float* row = &xs[hh * 64 + w4];
      float4 va = *reinterpret_cast<const float4*>(row);
      float4 vb = *reinterpret_cast<const float4*>(row + 4);
      float v0 = va.x, v1 = va.y, v2 = va.z, v3 = va.w;
      float v4 = vb.x, v5 = vb.y, v6 = vb.z, v7 = vb.w;
      float u0 = wr[dh * 5 + 0], u1 = wr[dh * 5 + 1], u2 = wr[dh * 5 + 2];
      float u3 = wr[dh * 5 + 3], u4 = wr[dh * 5 + 4];
      a0 += v0 * u0 + v1 * u1 + v2 * u2 + v3 * u3 + v4 * u4;
      a1 += v1 * u0 + v2 * u1 + v3 * u2 + v4 * u3 + v5 * u4;
      a2 += v2 * u0 + v3 * u1 + v4 * u2 + v5 * u3 + v6 * u4;
      a3 += v3 * u0 + v4 * u1 + v5 * u2 + v6 * u3 + v7 * u4;
    }
    size_t base = (size_t)bc * HW_ + h * W_ + w4;
    ushort4 pk = make_ushort4(f2bf_bits(a0), f2bf_bits(a1), f2bf_bits(a2), f2bf_bits(a3));
    *reinterpret_cast<ushort4*>(reinterpret_cast<unsigned short*>(z) + base) = pk;
  }
}

// ---------------- K3b: channel LN over z -> yT (bf16, [j][c], j=b*HW+hw) ----------------
__global__ __launch_bounds__(256) void ln_kernel(const bf16* __restrict__ z,
                                                 const float* __restrict__ ln2_w,
                                                 const float* __restrict__ ln2_b,
                                                 bf16* __restrict__ yT) {
  int hw0 = blockIdx.x * 64;
  int b = blockIdx.y;
  int tid = threadIdx.x;
  int wq = tid & 63;
  int cq = tid >> 6;
  __shared__ unsigned short zt[C_][64];
  __shared__ float redS[4][64];
  __shared__ float redQ[4][64];
  __shared__ float meanArr[64];
  __shared__ float invArr[64];
  float s = 0.f, q = 0.f;
  const unsigned short* zp = reinterpret_cast<const unsigned short*>(z);
#pragma unroll 4
  for (int k = 0; k < 32; ++k) {
    int c = cq * 32 + k;
    unsigned short u = zp[((size_t)(b * C_ + c)) * HW_ + hw0 + wq];
    float v = bf2f(u);
    s += v;
    q += v * v;
    zt[c][wq] = u;
  }
  redS[cq][wq] = s;
  redQ[cq][wq] = q;
  __syncthreads();
  if (cq == 0) {
    float ss = redS[0][wq] + redS[1][wq] + redS[2][wq] + redS[3][wq];
    float qq = redQ[0][wq] + redQ[1][wq] + redQ[2][wq] + redQ[3][wq];
    float m = ss * (1.0f / C_);
    float var = qq * (1.0f / C_) - m * m;
    meanArr[wq] = m;
    invArr[wq] = rsqrtf(fmaxf(var, 0.f) + EPS_);
  }
  __syncthreads();
  float m = meanArr[wq], iv = invArr[wq];
  // write 32 contiguous c per thread into yT row j = b*HW + hw0 + wq
  unsigned short* yp =
      reinterpret_cast<unsigned short*>(yT) + ((size_t)(b * HW_ + hw0 + wq)) * C_ + cq * 32;
#pragma unroll
  for (int g = 0; g < 4; ++g) {
    unsigned short pk[8];
#pragma unroll
    for (int i = 0; i < 8; ++i) {
      int c = cq * 32 + g * 8 + i;
      float v = bf2f(zt[c][wq]);
      pk[i] = f2bf_bits((v - m) * iv * ln2_w[c] + ln2_b[c]);
    }
    int4 t;
    __builtin_memcpy(&t, pk, 16);
    *reinterpret_cast<int4*>(yp + g * 8) = t;
  }
}

// ---------------- K4: expand MFMA GEMM D[j][o] = yT[j][c] x weB^T + GELU + gx2 ----------------
// grid (784 j-tiles, 4 o-tiles); 128x128 tile, 4 waves 2x2, 4x4 16x16x32 frags each
__global__ __launch_bounds__(256) void expand_mfma(const bf16* __restrict__ yT,
                                                   const bf16* __restrict__ weB,
                                                   bf16* __restrict__ eT,
                                                   float* __restrict__ gx2) {
  int j0 = blockIdx.x * 128;
  int o0 = blockIdx.y * 128;
  int tid = threadIdx.x;
  int lane = tid & 63, wid = tid >> 6;
  int wm = wid >> 1, wn = wid & 1;
  int quad = lane >> 4, l15 = lane & 15;
  __shared__ short As[128][40];   // [j][c] rows padded to 80B: frag reads 2-way (free)
  __shared__ short Bs[128][40];   // [o][c]
  f32x4 acc[4][4] = {};
  const short* yTs = reinterpret_cast<const short*>(yT);
  const short* weS = reinterpret_cast<const short*>(weB);
  for (int k0 = 0; k0 < C_; k0 += 32) {
#pragma unroll
    for (int t = tid; t < 512; t += 256) {
      int r = t >> 2, ch = t & 3;
      int4 va = *reinterpret_cast<const int4*>(yTs + (size_t)(j0 + r) * C_ + k0 + ch * 8);
      *reinterpret_cast<int4*>(&As[r][ch * 8]) = va;
      int4 vb = *reinterpret_cast<const int4*>(weS + (size_t)(o0 + r) * C_ + k0 + ch * 8);
      *reinterpret_cast<int4*>(&Bs[r][ch * 8]) = vb;
    }
    __syncthreads();
    short8 a[4], bfr[4];
#pragma unroll
    for (int mf = 0; mf < 4; ++mf)
      a[mf] = *reinterpret_cast<const short8*>(&As[wm * 64 + mf * 16 + l15][quad * 8]);
#pragma unroll
    for (int nf = 0; nf < 4; ++nf)
      bfr[nf] = *reinterpret_cast<const short8*>(&Bs[wn * 64 + nf * 16 + l15][quad * 8]);
#pragma unroll
    for (int mf = 0; mf < 4; ++mf)
#pragma unroll
      for (int nf = 0; nf < 4; ++nf)
        acc[mf][nf] = __builtin_amdgcn_mfma_f32_16x16x32_bf16(a[mf], bfr[nf], acc[mf][nf], 0, 0, 0);
    __syncthreads();
  }
  // epilogue: GELU, bf16 store to eT[j][o], gx2 atomics
  unsigned short* eP = reinterpret_cast<unsigned short*>(eT);
#pragma unroll
  for (int mf = 0; mf < 4; ++mf) {
    int jm = j0 + wm * 64 + mf * 16;          // 16-aligned -> single b per m-frag
    int bb = jm / HW_;
    int jb = jm + quad * 4;
#pragma unroll
    for (int nf = 0; nf < 4; ++nf) {
      int o = o0 + wn * 64 + nf * 16 + l15;
      float g2 = 0.f;
#pragma unroll
      for (int r = 0; r < 4; ++r) {
        float ge = fast_gelu(acc[mf][nf][r]);
        g2 += ge * ge;
        eP[(size_t)(jb + r) * CE_ + o] = f2bf_bits(ge);
      }
      g2 += __shfl_xor(g2, 16, 64);
      g2 += __shfl_xor(g2, 32, 64);
      if (quad == 0) atomicAdd(&gx2[bb * CE_ + o], g2);
    }
  }
}

// ---------------- K5a: GRN per-batch scale ----------------
__global__ __launch_bounds__(512) void grn_scale_kernel(const float* __restrict__ gx2,
                                                        const float* __restrict__ gamma,
                                                        float* __restrict__ scale) {
  int b = blockIdx.x;
  int o = threadIdx.x;
  float gx = sqrtf(gx2[b * CE_ + o]);
  float s = wave_reduce_sum(gx);
  __shared__ float red[8];
  __shared__ float meansh;
  int lane = o & 63, wid = o >> 6;
  if (lane == 0) red[wid] = s;
  __syncthreads();
  if (o == 0) {
    float t = 0.f;
    for (int i = 0; i < 8; ++i) t += red[i];
    meansh = t * (1.0f / CE_);
  }
  __syncthreads();
  scale[b * CE_ + o] = 1.0f + gamma[o] * (gx / (meansh + EPS_));
}

// ---------------- K5b: sb[c] = sum_o w_shrink[c,o] * beta[o] ----------------
__global__ __launch_bounds__(128) void sb_kernel(const float* __restrict__ w_shrink,
                                                 const float* __restrict__ beta,
                                                 float* __restrict__ sb) {
  int c = threadIdx.x;
  float acc = 0.f;
  for (int o = 0; o < CE_; ++o) acc += w_shrink[c * CE_ + o] * beta[o];
  sb[c] = acc;
}

// ---------------- K6: shrink MFMA GEMM out[j][c] = (scale*eT)[j][o] x wsB^T + sb + x ----------------
// grid (784 j-tiles); K=512, scale folded into A staging
__global__ __launch_bounds__(256) void shrink_mfma(const bf16* __restrict__ eT,
                                                   const bf16* __restrict__ wsB,
                                                   const float* __restrict__ scale,
                                                   const float* __restrict__ sb,
                                                   const float* __restrict__ x,
                                                   float* __restrict__ out) {
  int j0 = blockIdx.x * 128;
  int tid = threadIdx.x;
  int lane = tid & 63, wid = tid >> 6;
  int wm = wid >> 1, wn = wid & 1;
  int quad = lane >> 4, l15 = lane & 15;
  __shared__ short As[128][40];   // [j][o-chunk] (scale-folded)
  __shared__ short Bs[128][40];   // [c][o-chunk]
  f32x4 acc[4][4] = {};
  const short* eS = reinterpret_cast<const short*>(eT);
  const short* wsS = reinterpret_cast<const short*>(wsB);
  for (int k0 = 0; k0 < CE_; k0 += 32) {
#pragma unroll
    for (int t = tid; t < 512; t += 256) {
      int r = t >> 2, ch = t & 3;
      int jj = j0 + r;
      int bb = jj / HW_;
      union { int4 i4; unsigned short us[8]; } uv;
      uv.i4 = *reinterpret_cast<const int4*>(eS + (size_t)jj * CE_ + k0 + ch * 8);
      const float* sp = scale + bb * CE_ + k0 + ch * 8;
      unsigned short pk[8];
#pragma unroll
      for (int i = 0; i < 8; ++i) pk[i] = f2bf_bits(bf2f(uv.us[i]) * sp[i]);
      int4 t4;
      __builtin_memcpy(&t4, pk, 16);
      *reinterpret_cast<int4*>(&As[r][ch * 8]) = t4;
      int4 vb = *reinterpret_cast<const int4*>(wsS + (size_t)r * CE_ + k0 + ch * 8);
      *reinterpret_cast<int4*>(&Bs[r][ch * 8]) = vb;
    }
    __syncthreads();
    short8 a[4], bfr[4];
#pragma unroll
    for (int mf = 0; mf < 4; ++mf)
      a[mf] = *reinterpret_cast<const short8*>(&As[wm * 64 + mf * 16 + l15][quad * 8]);
#pragma unroll
    for (int nf = 0; nf < 4; ++nf)
      bfr[nf] = *reinterpret_cast<const short8*>(&Bs[wn * 64 + nf * 16 + l15][quad * 8]);
#pragma unroll
    for (int mf = 0; mf < 4; ++mf)
#pragma unroll
      for (int nf = 0; nf < 4; ++nf)
        acc[mf][nf] = __builtin_amdgcn_mfma_f32_16x16x32_bf16(a[mf], bfr[nf], acc[mf][nf], 0, 0, 0);
    __syncthreads();
  }
  // epilogue: + sb[c] + x residual, fp32 out[b][c][hw]
#pragma unroll
  for (int mf = 0; mf < 4; ++mf) {
    int jb = j0 + wm * 64 + mf * 16 + quad * 4;
    int bb = jb / HW_;          // lane's 4 rows share b (boundaries 4-aligned)
    int hw = jb - bb * HW_;
#pragma unroll
    for (int nf = 0; nf < 4; ++nf) {
      int c = wn * 64 + nf * 16 + l15;
      size_t base = ((size_t)(bb * C_ + c)) * HW_ + hw;
      float add = sb[c];
      float4 xv = *reinterpret_cast<const float4*>(x + base);
      float4 ov;
      ov.x = acc[mf][nf][0] + add + xv.x;
      ov.y = acc[mf][nf][1] + add + xv.y;
      ov.z = acc[mf][nf][2] + add + xv.z;
      ov.w = acc[mf][nf][3] + add + xv.w;
      *reinterpret_cast<float4*>(out + base) = ov;
    }
  }
}

extern "C" void kernel_launch(void* const* d_in, const int* in_sizes, int n_in,
                              void* d_out, int out_size, void* d_ws, size_t ws_size,
                              hipStream_t stream) {
  (void)in_sizes; (void)n_in; (void)out_size; (void)ws_size;
  const float* x        = (const float*)d_in[0];
  const float* w_fc1    = (const float*)d_in[1];
  const float* ln1_w    = (const float*)d_in[2];
  const float* ln1_b    = (const float*)d_in[3];
  const float* w_fc2    = (const float*)d_in[4];
  const float* ln2_w    = (const float*)d_in[5];
  const float* ln2_b    = (const float*)d_in[6];
  const float* w_expand = (const float*)d_in[7];
  const float* w_shrink = (const float*)d_in[8];
  const float* gamma    = (const float*)d_in[9];
  const float* beta     = (const float*)d_in[10];
  float* out = (float*)d_out;

  char* ws = (char*)d_ws;
  float* pooled = (float*)(ws + 0);
  float* dyn    = (float*)(ws + 16384);
  float* gx2    = (float*)(ws + 425984);
  float* scale  = (float*)(ws + 491520);
  float* sb     = (float*)(ws + 557056);
  bf16*  weB    = (bf16*)(ws + 557568);
  bf16*  wsB    = (bf16*)(ws + 688640);
  bf16*  yT     = (bf16*)(ws + 819712);
  bf16*  eT     = (bf16*)(ws + 26509824);
  bf16*  z      = eT;   // alias: z dead before expand_mfma writes eT

  prep_kernel<<<256, 256, 0, stream>>>(w_expand, w_shrink, weB, wsB);
  pool_kernel<<<B_ * C_, 256, 0, stream>>>(x, pooled);
  fc_kernel<<<B_, 256, 0, stream>>>(pooled, w_fc1, ln1_w, ln1_b, w_fc2, dyn);
  conv_kernel<<<B_ * C_, 256, 0, stream>>>(x, dyn, z);
  ln_kernel<<<dim3(49, B_), 256, 0, stream>>>(z, ln2_w, ln2_b, yT);
  hipMemsetAsync(gx2, 0, B_ * CE_ * sizeof(float), stream);
  expand_mfma<<<dim3(784, 4), 256, 0, stream>>>(yT, weB, eT, gx2);
  grn_scale_kernel<<<B_, 512, 0, stream>>>(gx2, gamma, scale);
  sb_kernel<<<1, 128, 0, stream>>>(w_shrink, beta, sb);
  shrink_mfma<<<784, 256, 0, stream>>>(eT, wsB, scale, sb, x, out);
}

// Round 4
// 303.035 us; speedup vs baseline: 3.1713x; 1.0439x over previous
//
#include <hip/hip_runtime.h>
#include <hip/hip_bf16.h>

#define B_   32
#define C_   128
#define H_   56
#define W_   56
#define HW_  (H_*W_)
#define BHW_ (B_*HW_)        // 100352; 3136 = 196*16 (b-boundaries 16-aligned)
#define K5_  5
#define KK_  25
#define CR_  32
#define CE_  512
#define EPS_ 1e-6f

typedef __hip_bfloat16 bf16;
typedef __attribute__((ext_vector_type(8))) short short8;   // 8 bf16 (4 VGPRs)
typedef __attribute__((ext_vector_type(4))) float f32x4;

// ---------- workspace layout (bytes) ----------
// pooled fp32 [B*C]        @ 0         (16,384)
// dyn    fp32 [B*C*25]     @ 16,384    (409,600)
// gx2    fp32 [B*CE]       @ 425,984   (65,536)
// scale  fp32 [B*CE]       @ 491,520   (65,536)
// sb     fp32 [C]          @ 557,056   (512)
// weB    bf16 [CE*C]       @ 557,568   (131,072)
// wsB    bf16 [C*CE]       @ 688,640   (131,072)
// yT     bf16 [BHW][C]     @ 819,712   (25,690,112)
//   sws bf16 [B][C][CE] (4,194,304 B) ALIASES head of yT: yT dead after
//   expand_mfma; ln_kernel rewrites yT fully before expand on every call.
// eT     bf16 [BHW][CE]    @ 26,509,824 (102,760,448)  (z aliases head of eT)
// total: 129,270,272 bytes

__device__ __forceinline__ float wave_reduce_sum(float v) {
#pragma unroll
  for (int off = 32; off > 0; off >>= 1) v += __shfl_down(v, off, 64);
  return v;
}
__device__ __forceinline__ float bf2f(unsigned short u) {
  return __uint_as_float(((unsigned)u) << 16);
}
__device__ __forceinline__ unsigned short f2bf_bits(float f) {
  bf16 h = __float2bfloat16(f);
  unsigned short u;
  __builtin_memcpy(&u, &h, 2);
  return u;
}
// sigmoid-form GELU: v * sigmoid(1.702 v). ~5 VALU ops (exp + rcp + 2 mul + add).
// max |err| vs exact ~0.02 @ |v|~3.2; propagated to out ~ +0.01-0.03 absmax.
__device__ __forceinline__ float fast_gelu(float v) {
  float t = __expf(-1.702f * v);
  return v * __builtin_amdgcn_rcpf(1.0f + t);
}

// ---------------- K0: weight bf16 conversion ----------------
__global__ __launch_bounds__(256) void prep_kernel(const float* __restrict__ we,
                                                   const float* __restrict__ ws,
                                                   bf16* __restrict__ weB,
                                                   bf16* __restrict__ wsB) {
  int i = blockIdx.x * 256 + threadIdx.x;
  if (i < CE_ * C_) {
    weB[i] = __float2bfloat16(we[i]);
    wsB[i] = __float2bfloat16(ws[i]);
  }
}

// ---------------- K1: global average pool ----------------
__global__ __launch_bounds__(256) void pool_kernel(const float* __restrict__ x,
                                                   float* __restrict__ pooled) {
  int bc = blockIdx.x;
  const float* xp = x + (size_t)bc * HW_;
  float s = 0.f;
  for (int i = threadIdx.x; i < HW_; i += 256) s += xp[i];
  s = wave_reduce_sum(s);
  __shared__ float red[4];
  int lane = threadIdx.x & 63, wid = threadIdx.x >> 6;
  if (lane == 0) red[wid] = s;
  __syncthreads();
  if (threadIdx.x == 0) pooled[bc] = (red[0] + red[1] + red[2] + red[3]) * (1.0f / HW_);
}

// ---------------- K2: fc1 -> LN1 -> fc2 (dyn weights) ----------------
__global__ __launch_bounds__(256) void fc_kernel(const float* __restrict__ pooled,
                                                 const float* __restrict__ w_fc1,
                                                 const float* __restrict__ ln1_w,
                                                 const float* __restrict__ ln1_b,
                                                 const float* __restrict__ w_fc2,
                                                 float* __restrict__ dyn) {
  int b = blockIdx.x;
  int tid = threadIdx.x;
  __shared__ float sp[C_];
  __shared__ float sh[CR_];
  __shared__ float shn[CR_];
  __shared__ float stats[2];
  if (tid < C_) sp[tid] = pooled[b * C_ + tid];
  __syncthreads();
  if (tid < CR_) {
    float acc = 0.f;
    const float* wr = w_fc1 + tid * C_;
#pragma unroll 4
    for (int c = 0; c < C_; ++c) acc += sp[c] * wr[c];
    sh[tid] = acc;
  }
  __syncthreads();
  if (tid == 0) {
    float u = 0.f;
    for (int j = 0; j < CR_; ++j) u += sh[j];
    u *= (1.0f / CR_);
    float v = 0.f;
    for (int j = 0; j < CR_; ++j) { float d = sh[j] - u; v += d * d; }
    v *= (1.0f / CR_);
    stats[0] = u;
    stats[1] = rsqrtf(v + EPS_);
  }
  __syncthreads();
  if (tid < CR_) shn[tid] = (sh[tid] - stats[0]) * stats[1] * ln1_w[tid] + ln1_b[tid];
  __syncthreads();
  for (int i = tid; i < C_ * KK_; i += 256) {
    const float* wr = w_fc2 + i * CR_;
    float acc = 0.f;
#pragma unroll
    for (int j = 0; j < CR_; ++j) acc += shn[j] * wr[j];
    dyn[b * (C_ * KK_) + i] = acc;
  }
}

// ---------------- K3a: dynamic depthwise 5x5 conv -> z (bf16, [b][c][hw]) ----------------
__global__ __launch_bounds__(256) void conv_kernel(const float* __restrict__ x,
                                                   const float* __restrict__ dyn,
                                                   bf16* __restrict__ z) {
  int bc = blockIdx.x;
  int b = bc >> 7;
  int c = bc & 127;
  int tid = threadIdx.x;
  __shared__ float xs[H_ * 64];
  __shared__ float wks[KK_];
  if (tid < H_ * 4) {
    int r = tid >> 2, q = tid & 3;
    int col = (q < 2) ? q : (56 + q);
    xs[r * 64 + col] = 0.f;
  }
  if (tid < KK_) wks[tid] = dyn[b * (C_ * KK_) + c * KK_ + tid];
  const float4* xp4 = reinterpret_cast<const float4*>(x + (size_t)bc * HW_);
  for (int i = tid; i < 784; i += 256) {
    float4 v = xp4[i];
    int h = i / 14, w4 = (i % 14) * 4;
    float* dst = &xs[h * 64 + 2 + w4];
    dst[0] = v.x; dst[1] = v.y; dst[2] = v.z; dst[3] = v.w;
  }
  __syncthreads();
  float wr[KK_];
#pragma unroll
  for (int j = 0; j < KK_; ++j) wr[j] = wks[j];
  for (int g = tid; g < 784; g += 256) {
    int h = g / 14;
    int w4 = (g % 14) * 4;
    float a0 = 0.f, a1 = 0.f, a2 = 0.f, a3 = 0.f;
#pragma unroll
    for (int dh = 0; dh < K5_; ++dh) {
      int hh = h + dh - 2;
      if (hh < 0 || hh >= H_) continue;
      const float* row = &xs[hh * 64 + w4];
      float4 va = *reinterpret_cast<const float4*>(row);
      float4 vb = *reinterpret_cast<const float4*>(row + 4);
      float v0 = va.x, v1 = va.y, v2 = va.z, v3 = va.w;
      float v4 = vb.x, v5 = vb.y, v6 = vb.z, v7 = vb.w;
      float u0 = wr[dh * 5 + 0], u1 = wr[dh * 5 + 1], u2 = wr[dh * 5 + 2];
      float u3 = wr[dh * 5 + 3], u4 = wr[dh * 5 + 4];
      a0 += v0 * u0 + v1 * u1 + v2 * u2 + v3 * u3 + v4 * u4;
      a1 += v1 * u0 + v2 * u1 + v3 * u2 + v4 * u3 + v5 * u4;
      a2 += v2 * u0 + v3 * u1 + v4 * u2 + v5 * u3 + v6 * u4;
      a3 += v3 * u0 + v4 * u1 + v5 * u2 + v6 * u3 + v7 * u4;
    }
    size_t base = (size_t)bc * HW_ + h * W_ + w4;
    ushort4 pk = make_ushort4(f2bf_bits(a0), f2bf_bits(a1), f2bf_bits(a2), f2bf_bits(a3));
    *reinterpret_cast<ushort4*>(reinterpret_cast<unsigned short*>(z) + base) = pk;
  }
}

// ---------------- K3b: channel LN over z -> yT (bf16, [j][c], j=b*HW+hw) ----------------
__global__ __launch_bounds__(256) void ln_kernel(const bf16* __restrict__ z,
                                                 const float* __restrict__ ln2_w,
                                                 const float* __restrict__ ln2_b,
                                                 bf16* __restrict__ yT) {
  int hw0 = blockIdx.x * 64;
  int b = blockIdx.y;
  int tid = threadIdx.x;
  int wq = tid & 63;
  int cq = tid >> 6;
  __shared__ unsigned short zt[C_][64];
  __shared__ float redS[4][64];
  __shared__ float redQ[4][64];
  __shared__ float meanArr[64];
  __shared__ float invArr[64];
  float s = 0.f, q = 0.f;
  const unsigned short* zp = reinterpret_cast<const unsigned short*>(z);
#pragma unroll 4
  for (int k = 0; k < 32; ++k) {
    int c = cq * 32 + k;
    unsigned short u = zp[((size_t)(b * C_ + c)) * HW_ + hw0 + wq];
    float v = bf2f(u);
    s += v;
    q += v * v;
    zt[c][wq] = u;
  }
  redS[cq][wq] = s;
  redQ[cq][wq] = q;
  __syncthreads();
  if (cq == 0) {
    float ss = redS[0][wq] + redS[1][wq] + redS[2][wq] + redS[3][wq];
    float qq = redQ[0][wq] + redQ[1][wq] + redQ[2][wq] + redQ[3][wq];
    float m = ss * (1.0f / C_);
    float var = qq * (1.0f / C_) - m * m;
    meanArr[wq] = m;
    invArr[wq] = rsqrtf(fmaxf(var, 0.f) + EPS_);
  }
  __syncthreads();
  float m = meanArr[wq], iv = invArr[wq];
  unsigned short* yp =
      reinterpret_cast<unsigned short*>(yT) + ((size_t)(b * HW_ + hw0 + wq)) * C_ + cq * 32;
#pragma unroll
  for (int g = 0; g < 4; ++g) {
    unsigned short pk[8];
#pragma unroll
    for (int i = 0; i < 8; ++i) {
      int c = cq * 32 + g * 8 + i;
      float v = bf2f(zt[c][wq]);
      pk[i] = f2bf_bits((v - m) * iv * ln2_w[c] + ln2_b[c]);
    }
    int4 t;
    __builtin_memcpy(&t, pk, 16);
    *reinterpret_cast<int4*>(yp + g * 8) = t;
  }
}

// ---------------- K4: expand MFMA GEMM D[j][o] = yT[j][c] x weB^T + GELU + gx2 ----------------
__global__ __launch_bounds__(256, 4) void expand_mfma(const bf16* __restrict__ yT,
                                                      const bf16* __restrict__ weB,
                                                      bf16* __restrict__ eT,
                                                      float* __restrict__ gx2) {
  int j0 = blockIdx.x * 128;
  int o0 = blockIdx.y * 128;
  int tid = threadIdx.x;
  int lane = tid & 63, wid = tid >> 6;
  int wm = wid >> 1, wn = wid & 1;
  int quad = lane >> 4, l15 = lane & 15;
  __shared__ short As[128][40];
  __shared__ short Bs[128][40];
  f32x4 acc[4][4] = {};
  const short* yTs = reinterpret_cast<const short*>(yT);
  const short* weS = reinterpret_cast<const short*>(weB);
  for (int k0 = 0; k0 < C_; k0 += 32) {
#pragma unroll
    for (int t = tid; t < 512; t += 256) {
      int r = t >> 2, ch = t & 3;
      int4 va = *reinterpret_cast<const int4*>(yTs + (size_t)(j0 + r) * C_ + k0 + ch * 8);
      *reinterpret_cast<int4*>(&As[r][ch * 8]) = va;
      int4 vb = *reinterpret_cast<const int4*>(weS + (size_t)(o0 + r) * C_ + k0 + ch * 8);
      *reinterpret_cast<int4*>(&Bs[r][ch * 8]) = vb;
    }
    __syncthreads();
    short8 a[4], bfr[4];
#pragma unroll
    for (int mf = 0; mf < 4; ++mf)
      a[mf] = *reinterpret_cast<const short8*>(&As[wm * 64 + mf * 16 + l15][quad * 8]);
#pragma unroll
    for (int nf = 0; nf < 4; ++nf)
      bfr[nf] = *reinterpret_cast<const short8*>(&Bs[wn * 64 + nf * 16 + l15][quad * 8]);
#pragma unroll
    for (int mf = 0; mf < 4; ++mf)
#pragma unroll
      for (int nf = 0; nf < 4; ++nf)
        acc[mf][nf] = __builtin_amdgcn_mfma_f32_16x16x32_bf16(a[mf], bfr[nf], acc[mf][nf], 0, 0, 0);
    __syncthreads();
  }
  unsigned short* eP = reinterpret_cast<unsigned short*>(eT);
#pragma unroll
  for (int mf = 0; mf < 4; ++mf) {
    int jm = j0 + wm * 64 + mf * 16;
    int bb = jm / HW_;
    int jb = jm + quad * 4;
#pragma unroll
    for (int nf = 0; nf < 4; ++nf) {
      int o = o0 + wn * 64 + nf * 16 + l15;
      float g2 = 0.f;
#pragma unroll
      for (int r = 0; r < 4; ++r) {
        float ge = fast_gelu(acc[mf][nf][r]);
        g2 += ge * ge;
        eP[(size_t)(jb + r) * CE_ + o] = f2bf_bits(ge);
      }
      g2 += __shfl_xor(g2, 16, 64);
      g2 += __shfl_xor(g2, 32, 64);
      if (quad == 0) atomicAdd(&gx2[bb * CE_ + o], g2);
    }
  }
}

// ---------------- K5a: GRN per-batch scale ----------------
__global__ __launch_bounds__(512) void grn_scale_kernel(const float* __restrict__ gx2,
                                                        const float* __restrict__ gamma,
                                                        float* __restrict__ scale) {
  int b = blockIdx.x;
  int o = threadIdx.x;
  float gx = sqrtf(gx2[b * CE_ + o]);
  float s = wave_reduce_sum(gx);
  __shared__ float red[8];
  __shared__ float meansh;
  int lane = o & 63, wid = o >> 6;
  if (lane == 0) red[wid] = s;
  __syncthreads();
  if (o == 0) {
    float t = 0.f;
    for (int i = 0; i < 8; ++i) t += red[i];
    meansh = t * (1.0f / CE_);
  }
  __syncthreads();
  scale[b * CE_ + o] = 1.0f + gamma[o] * (gx / (meansh + EPS_));
}

// ---------------- K5b: sb[c] = sum_o w_shrink[c,o] * beta[o] ----------------
__global__ __launch_bounds__(128) void sb_kernel(const float* __restrict__ w_shrink,
                                                 const float* __restrict__ beta,
                                                 float* __restrict__ sb) {
  int c = threadIdx.x;
  float acc = 0.f;
  for (int o = 0; o < CE_; ++o) acc += w_shrink[c * CE_ + o] * beta[o];
  sb[c] = acc;
}

// ---------------- K5c: sws[b][c][o] = ws[c][o] * scale[b][o] (bf16) ----------------
__global__ __launch_bounds__(256) void scale_ws_kernel(const float* __restrict__ ws,
                                                       const float* __restrict__ scale,
                                                       bf16* __restrict__ sws) {
  int c = blockIdx.x;
  int b = blockIdx.y;
  const float* sp = scale + b * CE_;
  const float* wp = ws + (size_t)c * CE_;
  bf16* op = sws + ((size_t)(b * C_ + c)) * CE_;
  for (int i = threadIdx.x; i < CE_; i += 256)
    op[i] = __float2bfloat16(wp[i] * sp[i]);
}

// ---------------- K6: shrink MFMA GEMM out[j][c] = eT[j][o] x sws[b]^T + sb + x ----------------
// grid (25 j-tiles, 32 b): b block-uniform, scale prefolded into sws, pure-copy staging
__global__ __launch_bounds__(256, 4) void shrink_mfma(const bf16* __restrict__ eT,
                                                      const bf16* __restrict__ sws,
                                                      const float* __restrict__ sb,
                                                      const float* __restrict__ x,
                                                      float* __restrict__ out) {
  int hw0 = blockIdx.x * 128;   // 0..3072; last tile only rows 0..63 valid
  int b = blockIdx.y;
  int tid = threadIdx.x;
  int lane = tid & 63, wid = tid >> 6;
  int wm = wid >> 1, wn = wid & 1;
  int quad = lane >> 4, l15 = lane & 15;
  __shared__ short As[128][40];   // [j][o-chunk]
  __shared__ short Bs[128][40];   // [c][o-chunk]
  f32x4 acc[4][4] = {};
  const short* eS = reinterpret_cast<const short*>(eT) + (size_t)b * HW_ * CE_;
  const short* wsS = reinterpret_cast<const short*>(sws) + (size_t)b * C_ * CE_;
  for (int k0 = 0; k0 < CE_; k0 += 32) {
#pragma unroll
    for (int t = tid; t < 512; t += 256) {
      int r = t >> 2, ch = t & 3;
      int hwc = hw0 + r; if (hwc >= HW_) hwc = HW_ - 1;   // clamp (finite garbage, masked at store)
      int4 va = *reinterpret_cast<const int4*>(eS + (size_t)hwc * CE_ + k0 + ch * 8);
      *reinterpret_cast<int4*>(&As[r][ch * 8]) = va;
      int4 vb = *reinterpret_cast<const int4*>(wsS + (size_t)r * CE_ + k0 + ch * 8);
      *reinterpret_cast<int4*>(&Bs[r][ch * 8]) = vb;
    }
    __syncthreads();
    short8 a[4], bfr[4];
#pragma unroll
    for (int mf = 0; mf < 4; ++mf)
      a[mf] = *reinterpret_cast<const short8*>(&As[wm * 64 + mf * 16 + l15][quad * 8]);
#pragma unroll
    for (int nf = 0; nf < 4; ++nf)
      bfr[nf] = *reinterpret_cast<const short8*>(&Bs[wn * 64 + nf * 16 + l15][quad * 8]);
#pragma unroll
    for (int mf = 0; mf < 4; ++mf)
#pragma unroll
      for (int nf = 0; nf < 4; ++nf)
        acc[mf][nf] = __builtin_amdgcn_mfma_f32_16x16x32_bf16(a[mf], bfr[nf], acc[mf][nf], 0, 0, 0);
    __syncthreads();
  }
#pragma unroll
  for (int mf = 0; mf < 4; ++mf) {
    int hw = hw0 + wm * 64 + mf * 16 + quad * 4;
    if (hw >= HW_) continue;    // wave-uniform (boundary 64-aligned)
#pragma unroll
    for (int nf = 0; nf < 4; ++nf) {
      int c = wn * 64 + nf * 16 + l15;
      size_t base = ((size_t)(b * C_ + c)) * HW_ + hw;
      float add = sb[c];
      float4 xv = *reinterpret_cast<const float4*>(x + base);
      float4 ov;
      ov.x = acc[mf][nf][0] + add + xv.x;
      ov.y = acc[mf][nf][1] + add + xv.y;
      ov.z = acc[mf][nf][2] + add + xv.z;
      ov.w = acc[mf][nf][3] + add + xv.w;
      *reinterpret_cast<float4*>(out + base) = ov;
    }
  }
}

extern "C" void kernel_launch(void* const* d_in, const int* in_sizes, int n_in,
                              void* d_out, int out_size, void* d_ws, size_t ws_size,
                              hipStream_t stream) {
  (void)in_sizes; (void)n_in; (void)out_size; (void)ws_size;
  const float* x        = (const float*)d_in[0];
  const float* w_fc1    = (const float*)d_in[1];
  const float* ln1_w    = (const float*)d_in[2];
  const float* ln1_b    = (const float*)d_in[3];
  const float* w_fc2    = (const float*)d_in[4];
  const float* ln2_w    = (const float*)d_in[5];
  const float* ln2_b    = (const float*)d_in[6];
  const float* w_expand = (const float*)d_in[7];
  const float* w_shrink = (const float*)d_in[8];
  const float* gamma    = (const float*)d_in[9];
  const float* beta     = (const float*)d_in[10];
  float* out = (float*)d_out;

  char* ws = (char*)d_ws;
  float* pooled = (float*)(ws + 0);
  float* dyn    = (float*)(ws + 16384);
  float* gx2    = (float*)(ws + 425984);
  float* scale  = (float*)(ws + 491520);
  float* sb     = (float*)(ws + 557056);
  bf16*  weB    = (bf16*)(ws + 557568);
  bf16*  wsB    = (bf16*)(ws + 688640);   // kept for layout stability (unused by shrink now)
  bf16*  yT     = (bf16*)(ws + 819712);
  bf16*  sws    = (bf16*)(ws + 819712);   // alias: yT dead after expand_mfma
  bf16*  eT     = (bf16*)(ws + 26509824);
  bf16*  z      = eT;                     // alias: z dead before expand_mfma writes eT
  (void)wsB;

  prep_kernel<<<256, 256, 0, stream>>>(w_expand, w_shrink, weB, wsB);
  pool_kernel<<<B_ * C_, 256, 0, stream>>>(x, pooled);
  fc_kernel<<<B_, 256, 0, stream>>>(pooled, w_fc1, ln1_w, ln1_b, w_fc2, dyn);
  conv_kernel<<<B_ * C_, 256, 0, stream>>>(x, dyn, z);
  ln_kernel<<<dim3(49, B_), 256, 0, stream>>>(z, ln2_w, ln2_b, yT);
  hipMemsetAsync(gx2, 0, B_ * CE_ * sizeof(float), stream);
  expand_mfma<<<dim3(784, 4), 256, 0, stream>>>(yT, weB, eT, gx2);
  grn_scale_kernel<<<B_, 512, 0, stream>>>(gx2, gamma, scale);
  sb_kernel<<<1, 128, 0, stream>>>(w_shrink, beta, sb);
  scale_ws_kernel<<<dim3(C_, B_), 256, 0, stream>>>(w_shrink, scale, sws);
  shrink_mfma<<<dim3(25, B_), 256, 0, stream>>>(eT, sws, sb, x, out);
}

// Round 5
// 297.336 us; speedup vs baseline: 3.2321x; 1.0192x over previous
//
#include <hip/hip_runtime.h>
#include <hip/hip_bf16.h>

#define B_   32
#define C_   128
#define H_   56
#define W_   56
#define HW_  (H_*W_)
#define BHW_ (B_*HW_)        // 100352; 3136 = 196*16 (b-boundaries 16-aligned)
#define K5_  5
#define KK_  25
#define CR_  32
#define CE_  512
#define EPS_ 1e-6f

typedef __hip_bfloat16 bf16;
typedef __attribute__((ext_vector_type(8))) short short8;   // 8 bf16 (4 VGPRs)
typedef __attribute__((ext_vector_type(4))) float f32x4;

// ---------- workspace layout (bytes) ----------
// pooled fp32 [B*C]        @ 0         (16,384)
// dyn    fp32 [B*C*25]     @ 16,384    (409,600)
// gx2    fp32 [B*CE]       @ 425,984   (65,536)
// scale  fp32 [B*CE]       @ 491,520   (65,536)
// sb     fp32 [C]          @ 557,056   (512)
// weB    bf16 [CE*C]       @ 557,568   (131,072)
// (hole) 131,072           @ 688,640
// yT     bf16 [BHW][C]     @ 819,712   (25,690,112)
//   sws bf16 [B][C][CE] (4,194,304 B) ALIASES head of yT (yT dead after expand)
// eT     bf16 [BHW][CE]    @ 26,509,824 (102,760,448)  (z aliases head of eT)

__device__ __forceinline__ float wave_reduce_sum(float v) {
#pragma unroll
  for (int off = 32; off > 0; off >>= 1) v += __shfl_down(v, off, 64);
  return v;
}
__device__ __forceinline__ float bf2f(unsigned short u) {
  return __uint_as_float(((unsigned)u) << 16);
}
__device__ __forceinline__ unsigned short f2bf_bits(float f) {
  bf16 h = __float2bfloat16(f);
  unsigned short u;
  __builtin_memcpy(&u, &h, 2);
  return u;
}
// sigmoid-form GELU: v * sigmoid(1.702 v)
__device__ __forceinline__ float fast_gelu(float v) {
  float t = __expf(-1.702f * v);
  return v * __builtin_amdgcn_rcpf(1.0f + t);
}

// ---------------- K0: weight bf16 conversion ----------------
__global__ __launch_bounds__(256) void prep_kernel(const float* __restrict__ we,
                                                   bf16* __restrict__ weB) {
  int i = blockIdx.x * 256 + threadIdx.x;
  if (i < CE_ * C_) weB[i] = __float2bfloat16(we[i]);
}

// ---------------- K1: global average pool ----------------
__global__ __launch_bounds__(256) void pool_kernel(const float* __restrict__ x,
                                                   float* __restrict__ pooled) {
  int bc = blockIdx.x;
  const float* xp = x + (size_t)bc * HW_;
  float s = 0.f;
  for (int i = threadIdx.x; i < HW_; i += 256) s += xp[i];
  s = wave_reduce_sum(s);
  __shared__ float red[4];
  int lane = threadIdx.x & 63, wid = threadIdx.x >> 6;
  if (lane == 0) red[wid] = s;
  __syncthreads();
  if (threadIdx.x == 0) pooled[bc] = (red[0] + red[1] + red[2] + red[3]) * (1.0f / HW_);
}

// ---------------- K2: fc1 -> LN1 -> fc2 (dyn weights) ----------------
__global__ __launch_bounds__(256) void fc_kernel(const float* __restrict__ pooled,
                                                 const float* __restrict__ w_fc1,
                                                 const float* __restrict__ ln1_w,
                                                 const float* __restrict__ ln1_b,
                                                 const float* __restrict__ w_fc2,
                                                 float* __restrict__ dyn) {
  int b = blockIdx.x;
  int tid = threadIdx.x;
  __shared__ float sp[C_];
  __shared__ float sh[CR_];
  __shared__ float shn[CR_];
  __shared__ float stats[2];
  if (tid < C_) sp[tid] = pooled[b * C_ + tid];
  __syncthreads();
  if (tid < CR_) {
    float acc = 0.f;
    const float* wr = w_fc1 + tid * C_;
#pragma unroll 4
    for (int c = 0; c < C_; ++c) acc += sp[c] * wr[c];
    sh[tid] = acc;
  }
  __syncthreads();
  if (tid == 0) {
    float u = 0.f;
    for (int j = 0; j < CR_; ++j) u += sh[j];
    u *= (1.0f / CR_);
    float v = 0.f;
    for (int j = 0; j < CR_; ++j) { float d = sh[j] - u; v += d * d; }
    v *= (1.0f / CR_);
    stats[0] = u;
    stats[1] = rsqrtf(v + EPS_);
  }
  __syncthreads();
  if (tid < CR_) shn[tid] = (sh[tid] - stats[0]) * stats[1] * ln1_w[tid] + ln1_b[tid];
  __syncthreads();
  for (int i = tid; i < C_ * KK_; i += 256) {
    const float* wr = w_fc2 + i * CR_;
    float acc = 0.f;
#pragma unroll
    for (int j = 0; j < CR_; ++j) acc += shn[j] * wr[j];
    dyn[b * (C_ * KK_) + i] = acc;
  }
}

// ---------------- K3a: dynamic depthwise 5x5 conv -> z (bf16, [b][c][hw]) ----------------
// halo rows AND cols zero-padded in LDS -> branch-free unrolled 5x5
__global__ __launch_bounds__(256) void conv_kernel(const float* __restrict__ x,
                                                   const float* __restrict__ dyn,
                                                   bf16* __restrict__ z) {
  int bc = blockIdx.x;
  int b = bc >> 7;
  int c = bc & 127;
  int tid = threadIdx.x;
  __shared__ float xs[(H_ + 4) * 64];   // rows -2..57 at (r+2)*64; 15,360 B
  __shared__ float wks[KK_];
  {  // zero halo rows 0,1,58,59 (full) — 4*64 = 256 = blockDim
    int r = tid >> 6;
    int rr = (r < 2) ? r : (56 + r);
    xs[rr * 64 + (tid & 63)] = 0.f;
  }
  if (tid < 224) {  // zero halo cols 0,1,58,59 of data rows 2..57
    int r = tid >> 2, q = tid & 3;
    int col = (q < 2) ? q : (56 + q);
    xs[(r + 2) * 64 + col] = 0.f;
  }
  if (tid < KK_) wks[tid] = dyn[b * (C_ * KK_) + c * KK_ + tid];
  const float4* xp4 = reinterpret_cast<const float4*>(x + (size_t)bc * HW_);
  for (int i = tid; i < 784; i += 256) {
    float4 v = xp4[i];
    int h = i / 14, w4 = (i % 14) * 4;
    float* dst = &xs[(h + 2) * 64 + 2 + w4];
    dst[0] = v.x; dst[1] = v.y; dst[2] = v.z; dst[3] = v.w;
  }
  __syncthreads();
  float wr[KK_];
#pragma unroll
  for (int j = 0; j < KK_; ++j) wr[j] = wks[j];
  for (int g = tid; g < 784; g += 256) {
    int h = g / 14;
    int w4 = (g % 14) * 4;
    float a0 = 0.f, a1 = 0.f, a2 = 0.f, a3 = 0.f;
#pragma unroll
    for (int dh = 0; dh < K5_; ++dh) {
      const float* row = &xs[(h + dh) * 64 + w4];   // padded row h+dh-2
      float4 va = *reinterpret_cast<const float4*>(row);
      float4 vb = *reinterpret_cast<const float4*>(row + 4);
      float v0 = va.x, v1 = va.y, v2 = va.z, v3 = va.w;
      float v4 = vb.x, v5 = vb.y, v6 = vb.z, v7 = vb.w;
      float u0 = wr[dh * 5 + 0], u1 = wr[dh * 5 + 1], u2 = wr[dh * 5 + 2];
      float u3 = wr[dh * 5 + 3], u4 = wr[dh * 5 + 4];
      a0 += v0 * u0 + v1 * u1 + v2 * u2 + v3 * u3 + v4 * u4;
      a1 += v1 * u0 + v2 * u1 + v3 * u2 + v4 * u3 + v5 * u4;
      a2 += v2 * u0 + v3 * u1 + v4 * u2 + v5 * u3 + v6 * u4;
      a3 += v3 * u0 + v4 * u1 + v5 * u2 + v6 * u3 + v7 * u4;
    }
    size_t base = (size_t)bc * HW_ + h * W_ + w4;
    ushort4 pk = make_ushort4(f2bf_bits(a0), f2bf_bits(a1), f2bf_bits(a2), f2bf_bits(a3));
    *reinterpret_cast<ushort4*>(reinterpret_cast<unsigned short*>(z) + base) = pk;
  }
}

// ---------------- K3b: channel LN over z -> yT (bf16, [j][c]); coalesced via LDS transpose ----------------
__global__ __launch_bounds__(256) void ln_kernel(const bf16* __restrict__ z,
                                                 const float* __restrict__ ln2_w,
                                                 const float* __restrict__ ln2_b,
                                                 bf16* __restrict__ yT) {
  int hw0 = blockIdx.x * 64;
  int b = blockIdx.y;
  int tid = threadIdx.x;
  int wq = tid & 63;
  int cq = tid >> 6;
  __shared__ unsigned short zt[C_][64];     // 16 KB
  __shared__ unsigned short yt[64][136];    // 17.4 KB transpose buffer (rows 16B-aligned)
  __shared__ float redS[4][64];
  __shared__ float redQ[4][64];
  __shared__ float meanArr[64];
  __shared__ float invArr[64];
  float s = 0.f, q = 0.f;
  const unsigned short* zp = reinterpret_cast<const unsigned short*>(z);
#pragma unroll 4
  for (int k = 0; k < 32; ++k) {
    int c = cq * 32 + k;
    unsigned short u = zp[((size_t)(b * C_ + c)) * HW_ + hw0 + wq];
    float v = bf2f(u);
    s += v;
    q += v * v;
    zt[c][wq] = u;
  }
  redS[cq][wq] = s;
  redQ[cq][wq] = q;
  __syncthreads();
  if (cq == 0) {
    float ss = redS[0][wq] + redS[1][wq] + redS[2][wq] + redS[3][wq];
    float qq = redQ[0][wq] + redQ[1][wq] + redQ[2][wq] + redQ[3][wq];
    float m = ss * (1.0f / C_);
    float var = qq * (1.0f / C_) - m * m;
    meanArr[wq] = m;
    invArr[wq] = rsqrtf(fmaxf(var, 0.f) + EPS_);
  }
  __syncthreads();
  float m = meanArr[wq], iv = invArr[wq];
#pragma unroll
  for (int g = 0; g < 4; ++g) {
    unsigned short pk[8];
#pragma unroll
    for (int i = 0; i < 8; ++i) {
      int c = cq * 32 + g * 8 + i;
      float v = bf2f(zt[c][wq]);
      pk[i] = f2bf_bits((v - m) * iv * ln2_w[c] + ln2_b[c]);
    }
    int4 t;
    __builtin_memcpy(&t, pk, 16);
    *reinterpret_cast<int4*>(&yt[wq][cq * 32 + g * 8]) = t;
  }
  __syncthreads();
  // store: 64 rows x 256B, 16 chunks/row -> 4 full rows per wave-instruction
  unsigned short* yp = reinterpret_cast<unsigned short*>(yT);
#pragma unroll
  for (int i = 0; i < 4; ++i) {
    int t = tid + 256 * i;
    int row = t >> 4, ch = t & 15;
    int4 v = *reinterpret_cast<const int4*>(&yt[row][ch * 8]);
    *reinterpret_cast<int4*>(yp + ((size_t)(b * HW_ + hw0 + row)) * C_ + ch * 8) = v;
  }
}

// ---------------- K4: expand MFMA GEMM + GELU + gx2; coalesced eT stores via LDS transpose ----------------
__global__ __launch_bounds__(256, 4) void expand_mfma(const bf16* __restrict__ yT,
                                                      const bf16* __restrict__ weB,
                                                      bf16* __restrict__ eT,
                                                      float* __restrict__ gx2) {
  int j0 = blockIdx.x * 128;
  int o0 = blockIdx.y * 128;
  int tid = threadIdx.x;
  int lane = tid & 63, wid = tid >> 6;
  int wm = wid >> 1, wn = wid & 1;
  int quad = lane >> 4, l15 = lane & 15;
  __shared__ __align__(16) char smem[128 * 136 * 2];   // union: As+Bs (20,480) / Es (34,816)
  short (*As)[40] = reinterpret_cast<short(*)[40]>(&smem[0]);
  short (*Bs)[40] = reinterpret_cast<short(*)[40]>(&smem[10240]);
  f32x4 acc[4][4] = {};
  const short* yTs = reinterpret_cast<const short*>(yT);
  const short* weS = reinterpret_cast<const short*>(weB);
  for (int k0 = 0; k0 < C_; k0 += 32) {
#pragma unroll
    for (int t = tid; t < 512; t += 256) {
      int r = t >> 2, ch = t & 3;
      int4 va = *reinterpret_cast<const int4*>(yTs + (size_t)(j0 + r) * C_ + k0 + ch * 8);
      *reinterpret_cast<int4*>(&As[r][ch * 8]) = va;
      int4 vb = *reinterpret_cast<const int4*>(weS + (size_t)(o0 + r) * C_ + k0 + ch * 8);
      *reinterpret_cast<int4*>(&Bs[r][ch * 8]) = vb;
    }
    __syncthreads();
    short8 a[4], bfr[4];
#pragma unroll
    for (int mf = 0; mf < 4; ++mf)
      a[mf] = *reinterpret_cast<const short8*>(&As[wm * 64 + mf * 16 + l15][quad * 8]);
#pragma unroll
    for (int nf = 0; nf < 4; ++nf)
      bfr[nf] = *reinterpret_cast<const short8*>(&Bs[wn * 64 + nf * 16 + l15][quad * 8]);
#pragma unroll
    for (int mf = 0; mf < 4; ++mf)
#pragma unroll
      for (int nf = 0; nf < 4; ++nf)
        acc[mf][nf] = __builtin_amdgcn_mfma_f32_16x16x32_bf16(a[mf], bfr[nf], acc[mf][nf], 0, 0, 0);
    __syncthreads();
  }
  // epilogue: GELU + gx2 from regs, then bf16 transpose tile -> coalesced 256B-row stores
  short (*Es)[136] = reinterpret_cast<short(*)[136]>(&smem[0]);   // As/Bs dead
#pragma unroll
  for (int mf = 0; mf < 4; ++mf) {
    int jm = j0 + wm * 64 + mf * 16;       // 16-aligned -> single b per m-frag
    int bb = jm / HW_;
    int jrow = wm * 64 + mf * 16 + quad * 4;
#pragma unroll
    for (int nf = 0; nf < 4; ++nf) {
      int oc = wn * 64 + nf * 16 + l15;
      float g2 = 0.f;
#pragma unroll
      for (int r = 0; r < 4; ++r) {
        float ge = fast_gelu(acc[mf][nf][r]);
        g2 += ge * ge;
        Es[jrow + r][oc] = (short)f2bf_bits(ge);
      }
      g2 += __shfl_xor(g2, 16, 64);
      g2 += __shfl_xor(g2, 32, 64);
      if (quad == 0) atomicAdd(&gx2[bb * CE_ + o0 + oc], g2);
    }
  }
  __syncthreads();
  unsigned short* eP = reinterpret_cast<unsigned short*>(eT);
#pragma unroll
  for (int i = 0; i < 8; ++i) {   // 128 rows x 16 chunks(16B): 4 full rows / wave-instr
    int t = tid + 256 * i;
    int row = t >> 4, ch = t & 15;
    int4 v = *reinterpret_cast<const int4*>(&Es[row][ch * 8]);
    *reinterpret_cast<int4*>(eP + (size_t)(j0 + row) * CE_ + o0 + ch * 8) = v;
  }
}

// ---------------- K5a: GRN per-batch scale ----------------
__global__ __launch_bounds__(512) void grn_scale_kernel(const float* __restrict__ gx2,
                                                        const float* __restrict__ gamma,
                                                        float* __restrict__ scale) {
  int b = blockIdx.x;
  int o = threadIdx.x;
  float gx = sqrtf(gx2[b * CE_ + o]);
  float s = wave_reduce_sum(gx);
  __shared__ float red[8];
  __shared__ float meansh;
  int lane = o & 63, wid = o >> 6;
  if (lane == 0) red[wid] = s;
  __syncthreads();
  if (o == 0) {
    float t = 0.f;
    for (int i = 0; i < 8; ++i) t += red[i];
    meansh = t * (1.0f / CE_);
  }
  __syncthreads();
  scale[b * CE_ + o] = 1.0f + gamma[o] * (gx / (meansh + EPS_));
}

// ---------------- K5b: sb[c] = sum_o w_shrink[c,o] * beta[o] ----------------
__global__ __launch_bounds__(128) void sb_kernel(const float* __restrict__ w_shrink,
                                                 const float* __restrict__ beta,
                                                 float* __restrict__ sb) {
  int c = threadIdx.x;
  float acc = 0.f;
  for (int o = 0; o < CE_; ++o) acc += w_shrink[c * CE_ + o] * beta[o];
  sb[c] = acc;
}

// ---------------- K5c: sws[b][c][o] = ws[c][o] * scale[b][o] (bf16) ----------------
__global__ __launch_bounds__(256) void scale_ws_kernel(const float* __restrict__ ws,
                                                       const float* __restrict__ scale,
                                                       bf16* __restrict__ sws) {
  int c = blockIdx.x;
  int b = blockIdx.y;
  const float* sp = scale + b * CE_;
  const float* wp = ws + (size_t)c * CE_;
  bf16* op = sws + ((size_t)(b * C_ + c)) * CE_;
  for (int i = threadIdx.x; i < CE_; i += 256)
    op[i] = __float2bfloat16(wp[i] * sp[i]);
}

// ---------------- K6: shrink MFMA GEMM + bias + residual; coalesced out via LDS transpose ----------------
__global__ __launch_bounds__(256, 4) void shrink_mfma(const bf16* __restrict__ eT,
                                                      const bf16* __restrict__ sws,
                                                      const float* __restrict__ sb,
                                                      const float* __restrict__ x,
                                                      float* __restrict__ out) {
  int hw0 = blockIdx.x * 128;   // last tile: rows 64..127 invalid
  int b = blockIdx.y;
  int tid = threadIdx.x;
  int lane = tid & 63, wid = tid >> 6;
  int wm = wid >> 1, wn = wid & 1;
  int quad = lane >> 4, l15 = lane & 15;
  __shared__ __align__(16) char smem[64 * 136 * 4];    // union: As+Bs (20,480) / Ef (34,816)
  short (*As)[40] = reinterpret_cast<short(*)[40]>(&smem[0]);
  short (*Bs)[40] = reinterpret_cast<short(*)[40]>(&smem[10240]);
  f32x4 acc[4][4] = {};
  const short* eS = reinterpret_cast<const short*>(eT) + (size_t)b * HW_ * CE_;
  const short* wsS = reinterpret_cast<const short*>(sws) + (size_t)b * C_ * CE_;
  for (int k0 = 0; k0 < CE_; k0 += 32) {
#pragma unroll
    for (int t = tid; t < 512; t += 256) {
      int r = t >> 2, ch = t & 3;
      int hwc = hw0 + r; if (hwc >= HW_) hwc = HW_ - 1;  // clamp, masked at store
      int4 va = *reinterpret_cast<const int4*>(eS + (size_t)hwc * CE_ + k0 + ch * 8);
      *reinterpret_cast<int4*>(&As[r][ch * 8]) = va;
      int4 vb = *reinterpret_cast<const int4*>(wsS + (size_t)r * CE_ + k0 + ch * 8);
      *reinterpret_cast<int4*>(&Bs[r][ch * 8]) = vb;
    }
    __syncthreads();
    short8 a[4], bfr[4];
#pragma unroll
    for (int mf = 0; mf < 4; ++mf)
      a[mf] = *reinterpret_cast<const short8*>(&As[wm * 64 + mf * 16 + l15][quad * 8]);
#pragma unroll
    for (int nf = 0; nf < 4; ++nf)
      bfr[nf] = *reinterpret_cast<const short8*>(&Bs[wn * 64 + nf * 16 + l15][quad * 8]);
#pragma unroll
    for (int mf = 0; mf < 4; ++mf)
#pragma unroll
      for (int nf = 0; nf < 4; ++nf)
        acc[mf][nf] = __builtin_amdgcn_mfma_f32_16x16x32_bf16(a[mf], bfr[nf], acc[mf][nf], 0, 0, 0);
    __syncthreads();
  }
  // two-phase f32 transpose: phase p handles c in [p*64, p*64+64)
  float (*Ef)[136] = reinterpret_cast<float(*)[136]>(&smem[0]);   // As/Bs dead
#pragma unroll
  for (int phase = 0; phase < 2; ++phase) {
    if (wn == phase) {
#pragma unroll
      for (int mf = 0; mf < 4; ++mf) {
        int hwr = wm * 64 + mf * 16 + quad * 4;
#pragma unroll
        for (int nf = 0; nf < 4; ++nf) {
          int cr = nf * 16 + l15;
          *reinterpret_cast<f32x4*>(&Ef[cr][hwr]) = acc[mf][nf];
        }
      }
    }
    __syncthreads();
    // store: 64 c-rows x 128 hw (512B), 32 chunks(16B)/row -> 2 full rows / wave-instr
#pragma unroll
    for (int i = 0; i < 8; ++i) {
      int t = tid + 256 * i;
      int row = t >> 5, ch = t & 31;
      int hw = hw0 + ch * 4;
      if (hw < HW_) {
        int c = phase * 64 + row;
        size_t base = ((size_t)(b * C_ + c)) * HW_ + hw;
        float add = sb[c];
        f32x4 av = *reinterpret_cast<const f32x4*>(&Ef[row][ch * 4]);
        float4 xv = *reinterpret_cast<const float4*>(x + base);
        float4 ov;
        ov.x = av.x + add + xv.x;
        ov.y = av.y + add + xv.y;
        ov.z = av.z + add + xv.z;
        ov.w = av.w + add + xv.w;
        *reinterpret_cast<float4*>(out + base) = ov;
      }
    }
    __syncthreads();
  }
}

extern "C" void kernel_launch(void* const* d_in, const int* in_sizes, int n_in,
                              void* d_out, int out_size, void* d_ws, size_t ws_size,
                              hipStream_t stream) {
  (void)in_sizes; (void)n_in; (void)out_size; (void)ws_size;
  const float* x        = (const float*)d_in[0];
  const float* w_fc1    = (const float*)d_in[1];
  const float* ln1_w    = (const float*)d_in[2];
  const float* ln1_b    = (const float*)d_in[3];
  const float* w_fc2    = (const float*)d_in[4];
  const float* ln2_w    = (const float*)d_in[5];
  const float* ln2_b    = (const float*)d_in[6];
  const float* w_expand = (const float*)d_in[7];
  const float* w_shrink = (const float*)d_in[8];
  const float* gamma    = (const float*)d_in[9];
  const float* beta     = (const float*)d_in[10];
  float* out = (float*)d_out;

  char* ws = (char*)d_ws;
  float* pooled = (float*)(ws + 0);
  float* dyn    = (float*)(ws + 16384);
  float* gx2    = (float*)(ws + 425984);
  float* scale  = (float*)(ws + 491520);
  float* sb     = (float*)(ws + 557056);
  bf16*  weB    = (bf16*)(ws + 557568);
  bf16*  yT     = (bf16*)(ws + 819712);
  bf16*  sws    = (bf16*)(ws + 819712);   // alias: yT dead after expand_mfma
  bf16*  eT     = (bf16*)(ws + 26509824);
  bf16*  z      = eT;                     // alias: z dead before expand_mfma writes eT

  prep_kernel<<<256, 256, 0, stream>>>(w_expand, weB);
  pool_kernel<<<B_ * C_, 256, 0, stream>>>(x, pooled);
  fc_kernel<<<B_, 256, 0, stream>>>(pooled, w_fc1, ln1_w, ln1_b, w_fc2, dyn);
  conv_kernel<<<B_ * C_, 256, 0, stream>>>(x, dyn, z);
  ln_kernel<<<dim3(49, B_), 256, 0, stream>>>(z, ln2_w, ln2_b, yT);
  hipMemsetAsync(gx2, 0, B_ * CE_ * sizeof(float), stream);
  expand_mfma<<<dim3(784, 4), 256, 0, stream>>>(yT, weB, eT, gx2);
  grn_scale_kernel<<<B_, 512, 0, stream>>>(gx2, gamma, scale);
  sb_kernel<<<1, 128, 0, stream>>>(w_shrink, beta, sb);
  scale_ws_kernel<<<dim3(C_, B_), 256, 0, stream>>>(w_shrink, scale, sws);
  shrink_mfma<<<dim3(25, B_), 256, 0, stream>>>(eT, sws, sb, x, out);
}